// Round 1
// baseline (370.886 us; speedup 1.0000x reference)
//
#include <hip/hip_runtime.h>
#include <stdint.h>

#define T_ 2048
#define E_ 1024

typedef __attribute__((ext_vector_type(8))) __bf16 bf16x8;
typedef __attribute__((ext_vector_type(4))) float f32x4;

__device__ __forceinline__ void gload_lds16(const void* g, void* l) {
  __builtin_amdgcn_global_load_lds(
      (const __attribute__((address_space(1))) unsigned int*)g,
      (__attribute__((address_space(3))) unsigned int*)l, 16, 0, 0);
}

// ---------------- fp32 -> bf16 hi/lo split ----------------
__global__ __launch_bounds__(256) void k_split(const float4* __restrict__ src,
                                               ushort4* __restrict__ hi,
                                               ushort4* __restrict__ lo, int n4) {
  int i = blockIdx.x * 256 + threadIdx.x;
  if (i >= n4) return;
  float4 x = src[i];
  float xs[4] = {x.x, x.y, x.z, x.w};
  union { __bf16 b[4]; ushort4 u; } H, L;
#pragma unroll
  for (int j = 0; j < 4; ++j) {
    __bf16 h = (__bf16)xs[j];
    H.b[j] = h;
    L.b[j] = (__bf16)(xs[j] - (float)h);
  }
  hi[i] = H.u;
  lo[i] = L.u;
}

// ---------------- fp32 -> bf16 plain ----------------
__global__ __launch_bounds__(256) void k_cvt(const float4* __restrict__ src,
                                             ushort4* __restrict__ dst, int n4) {
  int i = blockIdx.x * 256 + threadIdx.x;
  if (i >= n4) return;
  float4 x = src[i];
  float xs[4] = {x.x, x.y, x.z, x.w};
  union { __bf16 b[4]; ushort4 u; } H;
#pragma unroll
  for (int j = 0; j < 4; ++j) H.b[j] = (__bf16)xs[j];
  dst[i] = H.u;
}

// ---------------- cos/sin table (double precision) ----------------
__global__ __launch_bounds__(256) void k_table(float2* __restrict__ cs) {
  int i = blockIdx.x * 256 + threadIdx.x;  // 32768
  int t = i >> 4, f = i & 15;
  double inv = pow(10000.0, -(double)f / 16.0);
  double ang = (double)t * inv;
  cs[i] = make_float2((float)cos(ang), (float)sin(ang));
}

// ---------------- GEMM: C(M,N) = A(M,K) * W(N,K)^T, 128x128 tile ----------------
// EPI 0: fused RoPE + q-scale(log2e/8) + bf16 hi/lo split (scores in log2 domain)
template <int EPI, bool HILO>
__global__ __launch_bounds__(256) void k_gemm(const __bf16* __restrict__ Ah,
                                              const __bf16* __restrict__ Al,
                                              const __bf16* __restrict__ Bh,
                                              const __bf16* __restrict__ Bl,
                                              int M, int N, int K,
                                              const float2* __restrict__ cs,
                                              __bf16* __restrict__ qhi,
                                              __bf16* __restrict__ qlo,
                                              __bf16* __restrict__ khi,
                                              __bf16* __restrict__ klo,
                                              __bf16* __restrict__ v16,
                                              float* __restrict__ C32) {
  __shared__ __align__(16) __bf16 AsH[128 * 32];
  __shared__ __align__(16) __bf16 BsH[128 * 32];
  __shared__ __align__(16) __bf16 AsL[HILO ? 128 * 32 : 4];
  __shared__ __align__(16) __bf16 BsL[HILO ? 128 * 32 : 4];
  const int tid = threadIdx.x, lane = tid & 63, w = tid >> 6;
  const int wm = w >> 1, wn = w & 1;
  const int g = lane >> 4, d = lane & 15;
  const int m0 = blockIdx.y * 128, n0 = blockIdx.x * 128;

  f32x4 acc[4][4];
#pragma unroll
  for (int i = 0; i < 4; ++i)
#pragma unroll
    for (int j = 0; j < 4; ++j) acc[i][j] = (f32x4)(0.0f);

  const int row0 = tid >> 2, kc = tid & 3;
  const int row1 = 64 + row0;

  for (int k0 = 0; k0 < K; k0 += 32) {
    __syncthreads();
    gload_lds16(Ah + (size_t)(m0 + row0) * K + k0 + kc * 8, &AsH[w * 512]);
    gload_lds16(Ah + (size_t)(m0 + row1) * K + k0 + kc * 8, &AsH[2048 + w * 512]);
    gload_lds16(Bh + (size_t)(n0 + row0) * K + k0 + kc * 8, &BsH[w * 512]);
    gload_lds16(Bh + (size_t)(n0 + row1) * K + k0 + kc * 8, &BsH[2048 + w * 512]);
    if constexpr (HILO) {
      gload_lds16(Al + (size_t)(m0 + row0) * K + k0 + kc * 8, &AsL[w * 512]);
      gload_lds16(Al + (size_t)(m0 + row1) * K + k0 + kc * 8, &AsL[2048 + w * 512]);
      gload_lds16(Bl + (size_t)(n0 + row0) * K + k0 + kc * 8, &BsL[w * 512]);
      gload_lds16(Bl + (size_t)(n0 + row1) * K + k0 + kc * 8, &BsL[2048 + w * 512]);
    }
    __syncthreads();
    bf16x8 ah[4], bh[4], al[4], bl[4];
#pragma unroll
    for (int i = 0; i < 4; ++i) {
      ah[i] = *(const bf16x8*)&AsH[(wm * 64 + i * 16 + d) * 32 + g * 8];
      bh[i] = *(const bf16x8*)&BsH[(wn * 64 + i * 16 + d) * 32 + g * 8];
      if constexpr (HILO) {
        al[i] = *(const bf16x8*)&AsL[(wm * 64 + i * 16 + d) * 32 + g * 8];
        bl[i] = *(const bf16x8*)&BsL[(wn * 64 + i * 16 + d) * 32 + g * 8];
      }
    }
#pragma unroll
    for (int i = 0; i < 4; ++i)
#pragma unroll
      for (int j = 0; j < 4; ++j) {
        acc[i][j] = __builtin_amdgcn_mfma_f32_16x16x32_bf16(ah[i], bh[j], acc[i][j], 0, 0, 0);
        if constexpr (HILO) {
          acc[i][j] = __builtin_amdgcn_mfma_f32_16x16x32_bf16(al[i], bh[j], acc[i][j], 0, 0, 0);
          acc[i][j] = __builtin_amdgcn_mfma_f32_16x16x32_bf16(ah[i], bl[j], acc[i][j], 0, 0, 0);
        }
      }
  }

#pragma unroll
  for (int i = 0; i < 4; ++i) {
    const int rbase = m0 + wm * 64 + i * 16 + g * 4;
#pragma unroll
    for (int j = 0; j < 4; ++j) {
      const int col = n0 + wn * 64 + j * 16 + d;
#pragma unroll
      for (int r = 0; r < 4; ++r) {
        const float vv = acc[i][j][r];
        const int row = rbase + r;
        if constexpr (EPI == 0) {
          // RoPE pair partner (cl^1) lives at lane^1, same fragment reg
          const float xp = __shfl_xor(vv, 1);
          const int which = col >> 10;  // 0=q, 1=k
          const int cl = col & 1023;
          const int d2 = cl & 63;
          const int t2 = (row & 127) * 16 + (cl >> 6);  // reshaped position
          float y;
          if (d2 < 32) {
            const float2 cse = cs[t2 * 16 + (d2 >> 1)];
            y = (d2 & 1) ? (vv * cse.x + xp * cse.y) : (vv * cse.x - xp * cse.y);
          } else {
            y = vv;
          }
          if (which == 0) y *= 0.18033688011112042f;  // log2(e)/8: scores in log2 domain
          const __bf16 hi = (__bf16)y;
          const __bf16 lo = (__bf16)(y - (float)hi);
          const size_t off = (size_t)row * 1024 + cl;  // flat == [panel][t2][d2]
          (which ? khi : qhi)[off] = hi;
          (which ? klo : qlo)[off] = lo;
        } else if constexpr (EPI == 1) {
          C32[(size_t)row * N + col] = vv;
        } else {
          v16[(size_t)row * N + col] = (__bf16)vv;
        }
      }
    }
  }
}

// ---------------- V transpose: v16[p][t][d] -> v16t[p][d][t] ----------------
__global__ __launch_bounds__(256) void k_vtrans(const __bf16* __restrict__ v16,
                                                __bf16* __restrict__ v16t) {
  __shared__ __bf16 TB[64][72];
  const int p = blockIdx.y, t0 = blockIdx.x * 64;
  const int tid = threadIdx.x;
  const int r = tid >> 2, c4 = (tid & 3) * 16;
  const __bf16* src = v16 + ((size_t)p * 2048 + t0 + r) * 64 + c4;
  bf16x8 A = *(const bf16x8*)src;
  bf16x8 B2 = *(const bf16x8*)(src + 8);
#pragma unroll
  for (int e = 0; e < 8; ++e) {
    TB[c4 + e][r] = A[e];
    TB[c4 + 8 + e][r] = B2[e];
  }
  __syncthreads();
  const int dd = tid >> 2, cc = (tid & 3) * 16;
  __bf16* dst = v16t + ((size_t)p * 64 + dd) * 2048 + t0 + cc;
  *(bf16x8*)dst = *(const bf16x8*)&TB[dd][cc];
  *(bf16x8*)(dst + 8) = *(const bf16x8*)&TB[dd][cc + 8];
}

// ---------------- causal flash attention ----------------
// 512 thr / 8 waves; QBLK=256; KVBLK=32 (was 64); all K/V buffers double-buffered,
// 1 barrier per 32-kv tile. LDS 32KB (was 66KB) and q-lo reloaded from L2 per rb
// (addresses identical every tile -> L2-hot) so that with __launch_bounds__(512,6)
// three blocks (24 waves) are resident per CU instead of two (16) -> latency hiding.
// SWAPPED QK^T: S^T = mfma(K, Q); in-register softmax in exp2 domain; defer-max
// THR=11.5; fully-masked rb iterations skipped. PL is per-wave [16][32] with XOR
// granule swizzle (granule G of row d stored at slot G^((d>>1)&3)).
__global__ __launch_bounds__(512, 6) void k_attn(const __bf16* __restrict__ qhi,
                                                 const __bf16* __restrict__ qlo,
                                                 const __bf16* __restrict__ khi,
                                                 const __bf16* __restrict__ klo,
                                                 const __bf16* __restrict__ v16t,
                                                 __bf16* __restrict__ x16,
                                                 float* __restrict__ po,
                                                 float* __restrict__ pm,
                                                 float* __restrict__ pl_) {
  __shared__ __align__(16) __bf16 KH[2][32 * 64];  // [kv][dim]
  __shared__ __align__(16) __bf16 KL[2][32 * 64];
  __shared__ __align__(16) __bf16 VT[2][64 * 32];  // [dv][kv]
  __shared__ __align__(16) __bf16 PL[8][16 * 32];  // per-wave P, xor-swizzled

  const int x = blockIdx.x, panel = blockIdx.y;
  int qt, c, nc;
  if (x < 16)      { qt = 7 - (x >> 2);        c = x & 3;        nc = 4; }
  else if (x < 20) { qt = 3 - ((x - 16) >> 1); c = (x - 16) & 1; nc = 2; }
  else             { qt = 21 - x;              c = 0;            nc = 1; }
  const int sg = x;
  const int q0 = qt * 256;
  const int jmax = 4 * qt + 3;  // in 64-wide units; tiles are 2*jj and 2*jj+1

  const int tid = threadIdx.x, lane = tid & 63, w = tid >> 6;
  const int g = lane >> 4, d = lane & 15;
  const size_t hb = (size_t)panel * T_ * 64;

  // q-hi persistent in registers; q-lo reloaded per rb (same address every tile)
  bf16x8 qh[2][2];
#pragma unroll
  for (int rb = 0; rb < 2; ++rb) {
    const int rbi = w * 2 + rb;
    const size_t qrow = hb + (size_t)(q0 + rbi * 16 + d) * 64;
    qh[rb][0] = *(const bf16x8*)&qhi[qrow + g * 8];
    qh[rb][1] = *(const bf16x8*)&qhi[qrow + 32 + g * 8];
  }

  f32x4 o[2][4];
#pragma unroll
  for (int rb = 0; rb < 2; ++rb)
#pragma unroll
    for (int i = 0; i < 4; ++i) o[rb][i] = (f32x4)(0.0f);
  float m_[2] = {-__builtin_inff(), -__builtin_inff()};
  float l_[2] = {0.0f, 0.0f};

  const __bf16* kB = khi + hb;
  const __bf16* lB = klo + hb;
  const __bf16* vB = v16t + (size_t)panel * (64 * T_);
  const int dsw = (d >> 1) & 3;

  // Staging, per 32-kv tile: KH 4KB (waves 0-3), VT 4KB (waves 0-3), KL 4KB (waves 4-7).
  // gload_lds dest is wave-uniform base + lane*16; source is pre-swizzled so the
  // swizzled layout lands in a linear destination.
#define STAGE(tt, b)                                                              \
  {                                                                               \
    if (w < 4) {                                                                  \
      const int r_ = w * 8 + (lane >> 3);                                         \
      const int cg_ = ((lane & 7) ^ (r_ & 7)) * 8;                                \
      gload_lds16(kB + (size_t)((tt) * 32 + r_) * 64 + cg_, &KH[b][w * 512]);     \
      const int dv_ = w * 16 + (lane >> 2);                                       \
      const int vg_ = ((lane & 3) ^ ((dv_ >> 1) & 3)) * 8;                        \
      gload_lds16(vB + (size_t)dv_ * T_ + (tt) * 32 + vg_, &VT[b][w * 512]);      \
    } else {                                                                      \
      const int r_ = (w - 4) * 8 + (lane >> 3);                                   \
      const int cg_ = ((lane & 7) ^ (r_ & 7)) * 8;                                \
      gload_lds16(lB + (size_t)((tt) * 32 + r_) * 64 + cg_, &KL[b][(w - 4) * 512]); \
    }                                                                             \
  }

  STAGE(2 * c, 0);
  int cur = 0;
  for (int jj = c; jj <= jmax; jj += nc) {
#pragma unroll
    for (int h = 0; h < 2; ++h) {
      const int t = 2 * jj + h;  // 32-wide tile index
      __syncthreads();  // drains prefetch into buf[cur]; frees buf[cur^1]
      if (h == 0) {
        STAGE(t + 1, cur ^ 1);
      } else {
        const int jn = jj + nc;
        if (jn <= jmax) STAGE(2 * jn, cur ^ 1);
      }

#pragma unroll
      for (int rb = 0; rb < 2; ++rb) {
        const int rbi = w * 2 + rb;
        const int qrow0 = q0 + rbi * 16;
        if (t * 32 > qrow0 + 15) continue;  // fully masked rb: skip

        const size_t qrow = hb + (size_t)(qrow0 + d) * 64;
        const bf16x8 ql0 = *(const bf16x8*)&qlo[qrow + g * 8];
        const bf16x8 ql1 = *(const bf16x8*)&qlo[qrow + 32 + g * 8];

        f32x4 s[2];
        __builtin_amdgcn_s_setprio(1);
#pragma unroll
        for (int f = 0; f < 2; ++f) {
          f32x4 accs = (f32x4)(0.0f);
          const int colr = f * 16 + d;
#pragma unroll
          for (int ds = 0; ds < 2; ++ds) {
            const int slot = ((ds * 4 + g) ^ (colr & 7)) * 8;
            const bf16x8 kf = *(const bf16x8*)&KH[cur][colr * 64 + slot];
            const bf16x8 lf = *(const bf16x8*)&KL[cur][colr * 64 + slot];
            const bf16x8 qv = (ds == 0) ? ql0 : ql1;
            // SWAPPED: S^T[kv][q] — K is the A-operand, Q the B-operand
            accs = __builtin_amdgcn_mfma_f32_16x16x32_bf16(kf, qh[rb][ds], accs, 0, 0, 0);
            accs = __builtin_amdgcn_mfma_f32_16x16x32_bf16(kf, qv, accs, 0, 0, 0);
            accs = __builtin_amdgcn_mfma_f32_16x16x32_bf16(lf, qh[rb][ds], accs, 0, 0, 0);
          }
          s[f] = accs;
        }
        __builtin_amdgcn_s_setprio(0);

        if (t * 32 + 31 > qrow0) {  // diagonal-crossing tile: mask kv > q
          const int qq = qrow0 + d;
#pragma unroll
          for (int f = 0; f < 2; ++f)
#pragma unroll
            for (int r = 0; r < 4; ++r) {
              const int kv = t * 32 + f * 16 + g * 4 + r;
              if (kv > qq) s[f][r] = -30000.0f;  // sentinel (log2 domain), NaN-safe
            }
        }

        // in-register softmax: lane owns q-row d; reduce in-lane + across g
        float pmax = fmaxf(fmaxf(s[0][0], s[0][1]), fmaxf(s[0][2], s[0][3]));
        pmax = fmaxf(pmax, fmaxf(fmaxf(s[1][0], s[1][1]), fmaxf(s[1][2], s[1][3])));
        pmax = fmaxf(pmax, __shfl_xor(pmax, 16));
        pmax = fmaxf(pmax, __shfl_xor(pmax, 32));

        if (!__all(pmax - m_[rb] <= 11.5f)) {  // defer-max: rescale only on real growth
          const float mnew = fmaxf(m_[rb], pmax);
          const float fac = exp2f(m_[rb] - mnew);
          m_[rb] = mnew;
          float facr[4];
#pragma unroll
          for (int r = 0; r < 4; ++r)
            facr[r] = __shfl(fac, (lane & 48) | (g * 4 + r));  // fac for o-row g*4+r
#pragma unroll
          for (int ni = 0; ni < 4; ++ni)
#pragma unroll
            for (int r = 0; r < 4; ++r) o[rb][ni][r] *= facr[r];
          l_[rb] *= fac;
        }

        float sum = 0.0f;
#pragma unroll
        for (int f = 0; f < 2; ++f) {
          union { __bf16 b[4]; ushort4 u4; } pk;
#pragma unroll
          for (int r = 0; r < 4; ++r) {
            const float pv = exp2f(s[f][r] - m_[rb]);
            sum += pv;
            pk.b[r] = (__bf16)pv;
          }
          // granule fg = f*2+(g>>1) holds kv [fg*8, fg*8+8); xor-swizzled by row
          const int gsl = ((f * 2 + (g >> 1)) ^ dsw) * 8 + (g & 1) * 4;
          *(ushort4*)&PL[w][d * 32 + gsl] = pk.u4;
        }
        sum += __shfl_xor(sum, 16);
        sum += __shfl_xor(sum, 32);
        l_[rb] += sum;

        __builtin_amdgcn_s_setprio(1);
        const int vsl = (g ^ dsw) * 8;
        const bf16x8 pa = *(const bf16x8*)&PL[w][d * 32 + vsl];
#pragma unroll
        for (int ni = 0; ni < 4; ++ni) {
          const bf16x8 vf = *(const bf16x8*)&VT[cur][(ni * 16 + d) * 32 + vsl];
          o[rb][ni] = __builtin_amdgcn_mfma_f32_16x16x32_bf16(pa, vf, o[rb][ni], 0, 0, 0);
        }
        __builtin_amdgcn_s_setprio(0);
      }
      cur ^= 1;
    }
  }

  if (nc == 1) {
#pragma unroll
    for (int rb = 0; rb < 2; ++rb) {
      const int rbi = w * 2 + rb;
      float lr[4];
#pragma unroll
      for (int r = 0; r < 4; ++r)
        lr[r] = __shfl(l_[rb], (lane & 48) | (g * 4 + r));
#pragma unroll
      for (int ni = 0; ni < 4; ++ni)
#pragma unroll
        for (int r = 0; r < 4; ++r) {
          const size_t row = hb + (size_t)(q0 + rbi * 16 + g * 4 + r) * 64;
          x16[row + ni * 16 + d] = (__bf16)(o[rb][ni][r] / lr[r]);
        }
    }
  } else {
    const int slot = panel * 20 + sg;
#pragma unroll
    for (int rb = 0; rb < 2; ++rb) {
      const int rbi = w * 2 + rb;
#pragma unroll
      for (int ni = 0; ni < 4; ++ni)
#pragma unroll
        for (int r = 0; r < 4; ++r) {
          const int rowin = rbi * 16 + g * 4 + r;
          po[(size_t)slot * 16384 + rowin * 64 + ni * 16 + d] = o[rb][ni][r];
        }
      if (g == 0) {  // lane owns q-row d: one write per row
        pm[slot * 256 + rbi * 16 + d] = m_[rb];
        pl_[slot * 256 + rbi * 16 + d] = l_[rb];
      }
    }
  }
#undef STAGE
}

// ---------------- merge 2 or 4 KV-chunks for rows 512..2047 (log2 domain) ----------------
__global__ __launch_bounds__(256) void k_combine(const float* __restrict__ po,
                                                 const float* __restrict__ pm,
                                                 const float* __restrict__ pl_,
                                                 __bf16* __restrict__ x16) {
  const int p = blockIdx.y;
  const int li = blockIdx.x * 256 + threadIdx.x;  // 1536*64 per panel
  const int d = li & 63;
  const int t2 = 512 + (li >> 6);
  const int qt = t2 >> 8;                          // 2..7
  const int rowin = t2 & 255;
  const int nc = (qt >= 4) ? 4 : 2;
  const int base = (qt >= 4) ? (7 - qt) * 4 : 16 + (3 - qt) * 2;
  const int s0 = p * 20 + base;
  float M = -__builtin_inff();
  for (int s = 0; s < nc; ++s) M = fmaxf(M, pm[(s0 + s) * 256 + rowin]);
  float L = 0.0f, O = 0.0f;
  for (int s = 0; s < nc; ++s) {
    const float ww = exp2f(pm[(s0 + s) * 256 + rowin] - M);
    L += pl_[(s0 + s) * 256 + rowin] * ww;
    O += po[(size_t)(s0 + s) * 16384 + rowin * 64 + d] * ww;
  }
  x16[((size_t)p * T_ + t2) * 64 + d] = (__bf16)(O / L);
}

extern "C" void kernel_launch(void* const* d_in, const int* in_sizes, int n_in,
                              void* d_out, int out_size, void* d_ws, size_t ws_size,
                              hipStream_t stream) {
  const float* query = (const float*)d_in[0];
  const float* win = (const float*)d_in[4];
  const float* wout = (const float*)d_in[5];
  float* out = (float*)d_out;

  const size_t MB = 1024 * 1024;
  char* ws = (char*)d_ws;
  __bf16* xh = (__bf16*)(ws);              // 0-8   (dead after v-GEMM)
  __bf16* xl = (__bf16*)(ws + 8 * MB);     // 8-16
  __bf16* whh = (__bf16*)(ws + 16 * MB);   // 16-22
  __bf16* whl = (__bf16*)(ws + 22 * MB);   // 22-28
  __bf16* wob = (__bf16*)(ws + 28 * MB);   // 28-30
  float* pm = (float*)(ws + 30 * MB);      // 30-30.625 (640 slots x 256)
  float* pl_ = (float*)(ws + 30 * MB + 656 * 1024);
  float* po = (float*)(ws + 32 * MB);      // 32-72 (640 slots x 16384 f32 = 40MB)
  __bf16* qhi = (__bf16*)(ws + 72 * MB);
  __bf16* qlo = (__bf16*)(ws + 80 * MB);
  __bf16* khi = (__bf16*)(ws + 88 * MB);
  __bf16* klo = (__bf16*)(ws + 96 * MB);
  __bf16* x16 = (__bf16*)(ws + 104 * MB);
  float2* cs = (float2*)(ws + 112 * MB);
  __bf16* v16 = (__bf16*)(ws + 64 * MB);   // live only between v-GEMM and vtrans
  __bf16* v16t = (__bf16*)(ws);            // over xh, written after v-GEMM

  k_split<<<4096, 256, 0, stream>>>((const float4*)query, (ushort4*)xh, (ushort4*)xl,
                                    4096 * 1024 / 4);
  k_split<<<3072, 256, 0, stream>>>((const float4*)win, (ushort4*)whh, (ushort4*)whl,
                                    3072 * 1024 / 4);
  k_cvt<<<1024, 256, 0, stream>>>((const float4*)wout, (ushort4*)wob, 1024 * 1024 / 4);
  k_table<<<128, 256, 0, stream>>>(cs);

  // q,k projection with fused RoPE + hi/lo split (q pre-scaled by log2e/8)
  dim3 gqk(16, 32);
  k_gemm<0, true><<<gqk, 256, 0, stream>>>(xh, xl, whh, whl, 4096, 2048, 1024, cs,
                                           qhi, qlo, khi, klo, nullptr, nullptr);
  // v projection (plain bf16)
  dim3 gv(8, 32);
  k_gemm<2, false><<<gv, 256, 0, stream>>>(xh, nullptr, whh + (size_t)2048 * 1024, nullptr,
                                           4096, 1024, 1024, nullptr, nullptr, nullptr,
                                           nullptr, nullptr, v16, nullptr);

  dim3 gt(32, 32);
  k_vtrans<<<gt, 256, 0, stream>>>(v16, v16t);

  dim3 ga(22, 32);
  k_attn<<<ga, 512, 0, stream>>>(qhi, qlo, khi, klo, v16t, x16, po, pm, pl_);

  dim3 gc(384, 32);
  k_combine<<<gc, 256, 0, stream>>>(po, pm, pl_, x16);

  dim3 go(8, 32);
  k_gemm<1, false><<<go, 256, 0, stream>>>(x16, nullptr, wob, nullptr, 4096, 1024, 1024,
                                           nullptr, nullptr, nullptr, nullptr, nullptr,
                                           nullptr, out);
}

// Round 2
// 217.031 us; speedup vs baseline: 1.7089x; 1.7089x over previous
//
#include <hip/hip_runtime.h>
#include <stdint.h>

#define T_ 2048
#define E_ 1024

typedef __attribute__((ext_vector_type(8))) __bf16 bf16x8;
typedef __attribute__((ext_vector_type(4))) float f32x4;

__device__ __forceinline__ void gload_lds16(const void* g, void* l) {
  __builtin_amdgcn_global_load_lds(
      (const __attribute__((address_space(1))) unsigned int*)g,
      (__attribute__((address_space(3))) unsigned int*)l, 16, 0, 0);
}

// ---------------- fp32 -> bf16 hi/lo split ----------------
__global__ __launch_bounds__(256) void k_split(const float4* __restrict__ src,
                                               ushort4* __restrict__ hi,
                                               ushort4* __restrict__ lo, int n4) {
  int i = blockIdx.x * 256 + threadIdx.x;
  if (i >= n4) return;
  float4 x = src[i];
  float xs[4] = {x.x, x.y, x.z, x.w};
  union { __bf16 b[4]; ushort4 u; } H, L;
#pragma unroll
  for (int j = 0; j < 4; ++j) {
    __bf16 h = (__bf16)xs[j];
    H.b[j] = h;
    L.b[j] = (__bf16)(xs[j] - (float)h);
  }
  hi[i] = H.u;
  lo[i] = L.u;
}

// ---------------- fp32 -> bf16 plain ----------------
__global__ __launch_bounds__(256) void k_cvt(const float4* __restrict__ src,
                                             ushort4* __restrict__ dst, int n4) {
  int i = blockIdx.x * 256 + threadIdx.x;
  if (i >= n4) return;
  float4 x = src[i];
  float xs[4] = {x.x, x.y, x.z, x.w};
  union { __bf16 b[4]; ushort4 u; } H;
#pragma unroll
  for (int j = 0; j < 4; ++j) H.b[j] = (__bf16)xs[j];
  dst[i] = H.u;
}

// ---------------- cos/sin table (double precision) ----------------
__global__ __launch_bounds__(256) void k_table(float2* __restrict__ cs) {
  int i = blockIdx.x * 256 + threadIdx.x;  // 32768
  int t = i >> 4, f = i & 15;
  double inv = pow(10000.0, -(double)f / 16.0);
  double ang = (double)t * inv;
  cs[i] = make_float2((float)cos(ang), (float)sin(ang));
}

// ---------------- GEMM: C(M,N) = A(M,K) * W(N,K)^T, 128x128 tile ----------------
// EPI 0: fused RoPE + q-scale(log2e/8) + bf16 hi/lo split (scores in log2 domain)
template <int EPI, bool HILO>
__global__ __launch_bounds__(256) void k_gemm(const __bf16* __restrict__ Ah,
                                              const __bf16* __restrict__ Al,
                                              const __bf16* __restrict__ Bh,
                                              const __bf16* __restrict__ Bl,
                                              int M, int N, int K,
                                              const float2* __restrict__ cs,
                                              __bf16* __restrict__ qhi,
                                              __bf16* __restrict__ qlo,
                                              __bf16* __restrict__ khi,
                                              __bf16* __restrict__ klo,
                                              __bf16* __restrict__ v16,
                                              float* __restrict__ C32) {
  __shared__ __align__(16) __bf16 AsH[128 * 32];
  __shared__ __align__(16) __bf16 BsH[128 * 32];
  __shared__ __align__(16) __bf16 AsL[HILO ? 128 * 32 : 4];
  __shared__ __align__(16) __bf16 BsL[HILO ? 128 * 32 : 4];
  const int tid = threadIdx.x, lane = tid & 63, w = tid >> 6;
  const int wm = w >> 1, wn = w & 1;
  const int g = lane >> 4, d = lane & 15;
  const int m0 = blockIdx.y * 128, n0 = blockIdx.x * 128;

  f32x4 acc[4][4];
#pragma unroll
  for (int i = 0; i < 4; ++i)
#pragma unroll
    for (int j = 0; j < 4; ++j) acc[i][j] = (f32x4)(0.0f);

  const int row0 = tid >> 2, kc = tid & 3;
  const int row1 = 64 + row0;

  for (int k0 = 0; k0 < K; k0 += 32) {
    __syncthreads();
    gload_lds16(Ah + (size_t)(m0 + row0) * K + k0 + kc * 8, &AsH[w * 512]);
    gload_lds16(Ah + (size_t)(m0 + row1) * K + k0 + kc * 8, &AsH[2048 + w * 512]);
    gload_lds16(Bh + (size_t)(n0 + row0) * K + k0 + kc * 8, &BsH[w * 512]);
    gload_lds16(Bh + (size_t)(n0 + row1) * K + k0 + kc * 8, &BsH[2048 + w * 512]);
    if constexpr (HILO) {
      gload_lds16(Al + (size_t)(m0 + row0) * K + k0 + kc * 8, &AsL[w * 512]);
      gload_lds16(Al + (size_t)(m0 + row1) * K + k0 + kc * 8, &AsL[2048 + w * 512]);
      gload_lds16(Bl + (size_t)(n0 + row0) * K + k0 + kc * 8, &BsL[w * 512]);
      gload_lds16(Bl + (size_t)(n0 + row1) * K + k0 + kc * 8, &BsL[2048 + w * 512]);
    }
    __syncthreads();
    bf16x8 ah[4], bh[4], al[4], bl[4];
#pragma unroll
    for (int i = 0; i < 4; ++i) {
      ah[i] = *(const bf16x8*)&AsH[(wm * 64 + i * 16 + d) * 32 + g * 8];
      bh[i] = *(const bf16x8*)&BsH[(wn * 64 + i * 16 + d) * 32 + g * 8];
      if constexpr (HILO) {
        al[i] = *(const bf16x8*)&AsL[(wm * 64 + i * 16 + d) * 32 + g * 8];
        bl[i] = *(const bf16x8*)&BsL[(wn * 64 + i * 16 + d) * 32 + g * 8];
      }
    }
#pragma unroll
    for (int i = 0; i < 4; ++i)
#pragma unroll
      for (int j = 0; j < 4; ++j) {
        acc[i][j] = __builtin_amdgcn_mfma_f32_16x16x32_bf16(ah[i], bh[j], acc[i][j], 0, 0, 0);
        if constexpr (HILO) {
          acc[i][j] = __builtin_amdgcn_mfma_f32_16x16x32_bf16(al[i], bh[j], acc[i][j], 0, 0, 0);
          acc[i][j] = __builtin_amdgcn_mfma_f32_16x16x32_bf16(ah[i], bl[j], acc[i][j], 0, 0, 0);
        }
      }
  }

#pragma unroll
  for (int i = 0; i < 4; ++i) {
    const int rbase = m0 + wm * 64 + i * 16 + g * 4;
#pragma unroll
    for (int j = 0; j < 4; ++j) {
      const int col = n0 + wn * 64 + j * 16 + d;
#pragma unroll
      for (int r = 0; r < 4; ++r) {
        const float vv = acc[i][j][r];
        const int row = rbase + r;
        if constexpr (EPI == 0) {
          // RoPE pair partner (cl^1) lives at lane^1, same fragment reg
          const float xp = __shfl_xor(vv, 1);
          const int which = col >> 10;  // 0=q, 1=k
          const int cl = col & 1023;
          const int d2 = cl & 63;
          const int t2 = (row & 127) * 16 + (cl >> 6);  // reshaped position
          float y;
          if (d2 < 32) {
            const float2 cse = cs[t2 * 16 + (d2 >> 1)];
            y = (d2 & 1) ? (vv * cse.x + xp * cse.y) : (vv * cse.x - xp * cse.y);
          } else {
            y = vv;
          }
          if (which == 0) y *= 0.18033688011112042f;  // log2(e)/8: scores in log2 domain
          const __bf16 hi = (__bf16)y;
          const __bf16 lo = (__bf16)(y - (float)hi);
          const size_t off = (size_t)row * 1024 + cl;  // flat == [panel][t2][d2]
          (which ? khi : qhi)[off] = hi;
          (which ? klo : qlo)[off] = lo;
        } else if constexpr (EPI == 1) {
          C32[(size_t)row * N + col] = vv;
        } else {
          v16[(size_t)row * N + col] = (__bf16)vv;
        }
      }
    }
  }
}

// ---------------- V transpose: v16[p][t][d] -> v16t[p][d][t] ----------------
__global__ __launch_bounds__(256) void k_vtrans(const __bf16* __restrict__ v16,
                                                __bf16* __restrict__ v16t) {
  __shared__ __bf16 TB[64][72];
  const int p = blockIdx.y, t0 = blockIdx.x * 64;
  const int tid = threadIdx.x;
  const int r = tid >> 2, c4 = (tid & 3) * 16;
  const __bf16* src = v16 + ((size_t)p * 2048 + t0 + r) * 64 + c4;
  bf16x8 A = *(const bf16x8*)src;
  bf16x8 B2 = *(const bf16x8*)(src + 8);
#pragma unroll
  for (int e = 0; e < 8; ++e) {
    TB[c4 + e][r] = A[e];
    TB[c4 + 8 + e][r] = B2[e];
  }
  __syncthreads();
  const int dd = tid >> 2, cc = (tid & 3) * 16;
  __bf16* dst = v16t + ((size_t)p * 64 + dd) * 2048 + t0 + cc;
  *(bf16x8*)dst = *(const bf16x8*)&TB[dd][cc];
  *(bf16x8*)(dst + 8) = *(const bf16x8*)&TB[dd][cc + 8];
}

// ---------------- causal flash attention ----------------
// 512 thr / 8 waves; QBLK=256; KVBLK=64; double-buffered K/V, 1 barrier/tile.
// ROUND-0 inner structure (proven 80.5us): persistent qh+ql regs, 66KB LDS,
// launch_bounds(512,4) -> 2 blocks/CU. NEW: equal-work packing. Total work per
// panel = sum_qt (4qt+4) = 144 kv-tile units; cum(qt)=2qt(qt+1). Grid.x = 16
// blocks of EXACTLY 9 units each (16x32 = 512 blocks = exactly the 2/CU
// residency of 256 CUs -> no straggler tail). A block spans at most 2 q-tiles
// (2 sequential segments: reload Q, reset m/l/o, write partials). Slot = b+qt
// (23 slots/panel); k_combine merges ALL rows. Masked-row partials self-heal:
// m=-30000 sentinel partials get weight exp2(-30000-M)=0 in combine.
__global__ __launch_bounds__(512, 4) void k_attn(const __bf16* __restrict__ qhi,
                                                 const __bf16* __restrict__ qlo,
                                                 const __bf16* __restrict__ khi,
                                                 const __bf16* __restrict__ klo,
                                                 const __bf16* __restrict__ v16t,
                                                 __bf16* __restrict__ x16,
                                                 float* __restrict__ po,
                                                 float* __restrict__ pm,
                                                 float* __restrict__ pl_) {
  __shared__ __align__(16) __bf16 KH[2][64 * 64];
  __shared__ __align__(16) __bf16 KL[2][64 * 64];
  __shared__ __align__(16) __bf16 VT[2][64 * 64];
  __shared__ __align__(16) __bf16 PL[8][16 * 72];

  const int b = blockIdx.x, panel = blockIdx.y;
  const int u0 = 9 * b;
  // segment A q-tile: largest qt with cum(qt) = 2qt(qt+1) <= u0
  int qtA = 0;
  while (2 * (qtA + 1) * (qtA + 2) <= u0) ++qtA;
  const int cumA = 2 * qtA * (qtA + 1);
  const int cumB = 2 * (qtA + 1) * (qtA + 2);
  const int jloA = u0 - cumA;
  const bool two = (u0 + 9 > cumB);
  const int jhiA = two ? (cumB - 1 - cumA) : (u0 + 8 - cumA);
  const int jhiB = u0 + 8 - cumB;  // valid only if two

  const int tid = threadIdx.x, lane = tid & 63, w = tid >> 6;
  const int g = lane >> 4, d = lane & 15;
  const size_t hb = (size_t)panel * T_ * 64;

  const int kr = tid >> 3, kc = tid & 7;
  const int swz = (kc ^ (kr & 7)) * 8;
  const __bf16* kB = khi + hb;
  const __bf16* lB = klo + hb;
  const __bf16* vB = v16t + (size_t)panel * (64 * T_);

#define STAGE(j, bb)                                                        \
  {                                                                         \
    gload_lds16(kB + (size_t)((j) * 64 + kr) * 64 + swz, &KH[bb][w * 512]); \
    gload_lds16(lB + (size_t)((j) * 64 + kr) * 64 + swz, &KL[bb][w * 512]); \
    gload_lds16(vB + (size_t)kr * T_ + (j) * 64 + swz, &VT[bb][w * 512]);   \
  }

  int cur = 0;
  STAGE(jloA, 0);

  for (int seg = 0; seg < 2; ++seg) {
    if (seg && !two) break;
    const int qt = qtA + seg;
    const int jlo = seg ? 0 : jloA;
    const int jhi = seg ? jhiB : jhiA;
    const int q0 = qt << 8;

    // per-segment Q fragments (hi + lo persistent in registers)
    bf16x8 qh[2][2], ql[2][2];
#pragma unroll
    for (int rb = 0; rb < 2; ++rb) {
      const int rbi = w * 2 + rb;
      const size_t qrow = hb + (size_t)(q0 + rbi * 16 + d) * 64;
      qh[rb][0] = *(const bf16x8*)&qhi[qrow + g * 8];
      qh[rb][1] = *(const bf16x8*)&qhi[qrow + 32 + g * 8];
      ql[rb][0] = *(const bf16x8*)&qlo[qrow + g * 8];
      ql[rb][1] = *(const bf16x8*)&qlo[qrow + 32 + g * 8];
    }

    f32x4 o[2][4];
#pragma unroll
    for (int rb = 0; rb < 2; ++rb)
#pragma unroll
      for (int i = 0; i < 4; ++i) o[rb][i] = (f32x4)(0.0f);
    float m_[2] = {-__builtin_inff(), -__builtin_inff()};
    float l_[2] = {0.0f, 0.0f};

    for (int j = jlo; j <= jhi; ++j) {
      __syncthreads();  // drains prefetch into buf[cur]; frees buf[cur^1]
      if (j < jhi) {
        STAGE(j + 1, cur ^ 1);
      } else if (!seg && two) {
        STAGE(0, cur ^ 1);  // cross-segment prefetch (K/V depend only on j)
      }

#pragma unroll
      for (int rb = 0; rb < 2; ++rb) {
        const int rbi = w * 2 + rb;
        const int qrow0 = q0 + rbi * 16;
        if (j * 64 > qrow0 + 15) continue;  // fully masked rb: skip (partials stay safe)

        f32x4 s[4];
        __builtin_amdgcn_s_setprio(1);
#pragma unroll
        for (int f = 0; f < 4; ++f) {
          f32x4 accs = (f32x4)(0.0f);
          const int colr = f * 16 + d;
#pragma unroll
          for (int ds = 0; ds < 2; ++ds) {
            const int slot = ((ds * 4 + g) ^ (colr & 7)) * 8;
            const bf16x8 kf = *(const bf16x8*)&KH[cur][colr * 64 + slot];
            const bf16x8 lf = *(const bf16x8*)&KL[cur][colr * 64 + slot];
            // SWAPPED: S^T[kv][q] — K is the A-operand, Q the B-operand
            accs = __builtin_amdgcn_mfma_f32_16x16x32_bf16(kf, qh[rb][ds], accs, 0, 0, 0);
            accs = __builtin_amdgcn_mfma_f32_16x16x32_bf16(kf, ql[rb][ds], accs, 0, 0, 0);
            accs = __builtin_amdgcn_mfma_f32_16x16x32_bf16(lf, qh[rb][ds], accs, 0, 0, 0);
          }
          s[f] = accs;
        }
        __builtin_amdgcn_s_setprio(0);

        if (j * 64 + 63 > qrow0) {  // diagonal-crossing tile: mask kv > q
          const int qq = qrow0 + d;
#pragma unroll
          for (int f = 0; f < 4; ++f)
#pragma unroll
            for (int r = 0; r < 4; ++r) {
              const int kv = j * 64 + f * 16 + g * 4 + r;
              if (kv > qq) s[f][r] = -30000.0f;  // sentinel (log2 domain), NaN-safe
            }
        }

        // in-register softmax: lane owns q-row d; reduce in-lane + across g
        float pmax = fmaxf(fmaxf(s[0][0], s[0][1]), fmaxf(s[0][2], s[0][3]));
#pragma unroll
        for (int f = 1; f < 4; ++f)
          pmax = fmaxf(pmax, fmaxf(fmaxf(s[f][0], s[f][1]), fmaxf(s[f][2], s[f][3])));
        pmax = fmaxf(pmax, __shfl_xor(pmax, 16));
        pmax = fmaxf(pmax, __shfl_xor(pmax, 32));

        if (!__all(pmax - m_[rb] <= 11.5f)) {  // defer-max: rescale only on real growth
          const float mnew = fmaxf(m_[rb], pmax);
          const float fac = exp2f(m_[rb] - mnew);
          m_[rb] = mnew;
          float facr[4];
#pragma unroll
          for (int r = 0; r < 4; ++r)
            facr[r] = __shfl(fac, (lane & 48) | (g * 4 + r));  // fac for o-row g*4+r
#pragma unroll
          for (int ni = 0; ni < 4; ++ni)
#pragma unroll
            for (int r = 0; r < 4; ++r) o[rb][ni][r] *= facr[r];
          l_[rb] *= fac;
        }

        float sum = 0.0f;
#pragma unroll
        for (int f = 0; f < 4; ++f) {
          union { __bf16 b[4]; ushort4 u4; } pk;
#pragma unroll
          for (int r = 0; r < 4; ++r) {
            const float pv = exp2f(s[f][r] - m_[rb]);
            sum += pv;
            pk.b[r] = (__bf16)pv;
          }
          // P[q=d][kv=f*16+g*4 .. +4] packed: one ds_write_b64
          *(ushort4*)&PL[w][d * 72 + f * 16 + g * 4] = pk.u4;
        }
        sum += __shfl_xor(sum, 16);
        sum += __shfl_xor(sum, 32);
        l_[rb] += sum;

        __builtin_amdgcn_s_setprio(1);
#pragma unroll
        for (int ks = 0; ks < 2; ++ks) {
          const bf16x8 pa = *(const bf16x8*)&PL[w][d * 72 + ks * 32 + g * 8];
#pragma unroll
          for (int ni = 0; ni < 4; ++ni) {
            const bf16x8 vf =
                *(const bf16x8*)&VT[cur][(ni * 16 + d) * 64 + (((ks * 4 + g) ^ (d & 7)) * 8)];
            o[rb][ni] = __builtin_amdgcn_mfma_f32_16x16x32_bf16(pa, vf, o[rb][ni], 0, 0, 0);
          }
        }
        __builtin_amdgcn_s_setprio(0);
      }
      cur ^= 1;
    }

    // partial write for this segment; slot = b + qt (23 per panel)
    const int slot = panel * 23 + b + qt;
#pragma unroll
    for (int rb = 0; rb < 2; ++rb) {
      const int rbi = w * 2 + rb;
#pragma unroll
      for (int ni = 0; ni < 4; ++ni)
#pragma unroll
        for (int r = 0; r < 4; ++r) {
          const int rowin = rbi * 16 + g * 4 + r;
          po[(size_t)slot * 16384 + rowin * 64 + ni * 16 + d] = o[rb][ni][r];
        }
      if (g == 0) {  // lane owns q-row d: one write per row
        pm[slot * 256 + rbi * 16 + d] = m_[rb];
        pl_[slot * 256 + rbi * 16 + d] = l_[rb];
      }
    }
  }
#undef STAGE
}

// ---------------- merge KV-chunk partials for ALL rows (log2 domain) ----------------
// qt's chunks occupy slots [s0, s0+nc) with s0 = cum(qt)/9 + qt,
// nc = (cum(qt)+4qt+3)/9 - cum(qt)/9 + 1   (cum(qt) = 2qt(qt+1)).
__global__ __launch_bounds__(256) void k_combine(const float* __restrict__ po,
                                                 const float* __restrict__ pm,
                                                 const float* __restrict__ pl_,
                                                 __bf16* __restrict__ x16) {
  const int p = blockIdx.y;
  const int li = blockIdx.x * 256 + threadIdx.x;  // 2048*64 per panel
  const int d = li & 63;
  const int t2 = li >> 6;
  const int qt = t2 >> 8;
  const int rowin = t2 & 255;
  const int cq = 2 * qt * (qt + 1);
  const int nc = (cq + 4 * qt + 3) / 9 - cq / 9 + 1;
  const int s0 = p * 23 + cq / 9 + qt;
  float M = -__builtin_inff();
  for (int s = 0; s < nc; ++s) M = fmaxf(M, pm[(s0 + s) * 256 + rowin]);
  float L = 0.0f, O = 0.0f;
  for (int s = 0; s < nc; ++s) {
    const float ww = exp2f(pm[(s0 + s) * 256 + rowin] - M);
    L += pl_[(s0 + s) * 256 + rowin] * ww;
    O += po[(size_t)(s0 + s) * 16384 + rowin * 64 + d] * ww;
  }
  x16[((size_t)p * T_ + t2) * 64 + d] = (__bf16)(O / L);
}

extern "C" void kernel_launch(void* const* d_in, const int* in_sizes, int n_in,
                              void* d_out, int out_size, void* d_ws, size_t ws_size,
                              hipStream_t stream) {
  const float* query = (const float*)d_in[0];
  const float* win = (const float*)d_in[4];
  const float* wout = (const float*)d_in[5];
  float* out = (float*)d_out;

  const size_t MB = 1024 * 1024;
  const size_t KB = 1024;
  char* ws = (char*)d_ws;
  __bf16* xh = (__bf16*)(ws);                    // 0-8   (dead after v-GEMM)
  __bf16* xl = (__bf16*)(ws + 8 * MB);           // 8-16
  __bf16* whh = (__bf16*)(ws + 16 * MB);         // 16-22
  __bf16* whl = (__bf16*)(ws + 22 * MB);         // 22-28
  __bf16* wob = (__bf16*)(ws + 28 * MB);         // 28-30
  float* pm = (float*)(ws + 30 * MB);            // 736 slots x 256 f32 = 736KB
  float* pl_ = (float*)(ws + 30 * MB + 768 * KB);
  float2* cs = (float2*)(ws + 31 * MB + 512 * KB);  // 256KB, ends at 31.75MB
  float* po = (float*)(ws + 32 * MB);            // 736 slots x 16384 f32 = 46MB -> ends 78MB
  __bf16* qhi = (__bf16*)(ws + 78 * MB);         // 78-86
  __bf16* qlo = (__bf16*)(ws + 86 * MB);         // 86-94
  __bf16* khi = (__bf16*)(ws + 94 * MB);         // 94-102
  __bf16* klo = (__bf16*)(ws + 102 * MB);        // 102-110
  __bf16* x16 = (__bf16*)(ws + 78 * MB);         // alias qhi (dead after k_attn)
  __bf16* v16 = (__bf16*)(ws + 64 * MB);         // live only between v-GEMM and vtrans
  __bf16* v16t = (__bf16*)(ws);                  // over xh, written after v-GEMM

  k_split<<<4096, 256, 0, stream>>>((const float4*)query, (ushort4*)xh, (ushort4*)xl,
                                    4096 * 1024 / 4);
  k_split<<<3072, 256, 0, stream>>>((const float4*)win, (ushort4*)whh, (ushort4*)whl,
                                    3072 * 1024 / 4);
  k_cvt<<<1024, 256, 0, stream>>>((const float4*)wout, (ushort4*)wob, 1024 * 1024 / 4);
  k_table<<<128, 256, 0, stream>>>(cs);

  // q,k projection with fused RoPE + hi/lo split (q pre-scaled by log2e/8)
  dim3 gqk(16, 32);
  k_gemm<0, true><<<gqk, 256, 0, stream>>>(xh, xl, whh, whl, 4096, 2048, 1024, cs,
                                           qhi, qlo, khi, klo, nullptr, nullptr);
  // v projection (plain bf16)
  dim3 gv(8, 32);
  k_gemm<2, false><<<gv, 256, 0, stream>>>(xh, nullptr, whh + (size_t)2048 * 1024, nullptr,
                                           4096, 1024, 1024, nullptr, nullptr, nullptr,
                                           nullptr, nullptr, v16, nullptr);

  dim3 gt(32, 32);
  k_vtrans<<<gt, 256, 0, stream>>>(v16, v16t);

  dim3 ga(16, 32);  // 512 blocks == exact 2-blocks/CU residency, 9 units each
  k_attn<<<ga, 512, 0, stream>>>(qhi, qlo, khi, klo, v16t, x16, po, pm, pl_);

  dim3 gc(512, 32);  // all 2048 rows now combined
  k_combine<<<gc, 256, 0, stream>>>(po, pm, pl_, x16);

  dim3 go(8, 32);
  k_gemm<1, false><<<go, 256, 0, stream>>>(x16, nullptr, wob, nullptr, 4096, 1024, 1024,
                                           nullptr, nullptr, nullptr, nullptr, nullptr,
                                           nullptr, out);
}

// Round 3
// 211.657 us; speedup vs baseline: 1.7523x; 1.0254x over previous
//
#include <hip/hip_runtime.h>
#include <stdint.h>

#define T_ 2048
#define E_ 1024

typedef __attribute__((ext_vector_type(8))) __bf16 bf16x8;
typedef __attribute__((ext_vector_type(4))) float f32x4;

__device__ __forceinline__ void gload_lds16(const void* g, void* l) {
  __builtin_amdgcn_global_load_lds(
      (const __attribute__((address_space(1))) unsigned int*)g,
      (__attribute__((address_space(3))) unsigned int*)l, 16, 0, 0);
}

// ---------------- fused prep: hi/lo splits + wout cvt + cos/sin table ----------------
__global__ __launch_bounds__(256) void k_prep(const float4* __restrict__ q,
                                              ushort4* __restrict__ xh,
                                              ushort4* __restrict__ xl,
                                              const float4* __restrict__ win,
                                              ushort4* __restrict__ whh,
                                              ushort4* __restrict__ whl,
                                              const float4* __restrict__ wout,
                                              ushort4* __restrict__ wob,
                                              float2* __restrict__ cs) {
  const int b = blockIdx.x, tid = threadIdx.x;
  if (b < 7168) {  // hi/lo split: query (4096 blocks) then in_proj weights (3072)
    const float4* src;
    ushort4 *hi, *lo;
    int i;
    if (b < 4096) { src = q; hi = xh; lo = xl; i = b * 256 + tid; }
    else          { src = win; hi = whh; lo = whl; i = (b - 4096) * 256 + tid; }
    float4 x = src[i];
    float xs[4] = {x.x, x.y, x.z, x.w};
    union { __bf16 bb[4]; ushort4 u; } H, L;
#pragma unroll
    for (int jj = 0; jj < 4; ++jj) {
      __bf16 h = (__bf16)xs[jj];
      H.bb[jj] = h;
      L.bb[jj] = (__bf16)(xs[jj] - (float)h);
    }
    hi[i] = H.u;
    lo[i] = L.u;
  } else if (b < 8192) {  // wout plain cvt (1024 blocks)
    int i = (b - 7168) * 256 + tid;
    float4 x = wout[i];
    float xs[4] = {x.x, x.y, x.z, x.w};
    union { __bf16 bb[4]; ushort4 u; } H;
#pragma unroll
    for (int jj = 0; jj < 4; ++jj) H.bb[jj] = (__bf16)xs[jj];
    wob[i] = H.u;
  } else {  // cos/sin table, double precision (128 blocks)
    int i = (b - 8192) * 256 + tid;
    int t = i >> 4, f = i & 15;
    double inv = pow(10000.0, -(double)f / 16.0);
    double ang = (double)t * inv;
    cs[i] = make_float2((float)cos(ang), (float)sin(ang));
  }
}

// ---------------- GEMM: C(M,N) = A(M,K) * W(N,K)^T, 128x128 tile ----------------
// EPI 0: fused RoPE + q-scale(log2e/8) + bf16 hi/lo split (scores in log2 domain)
template <int EPI, bool HILO>
__global__ __launch_bounds__(256) void k_gemm(const __bf16* __restrict__ Ah,
                                              const __bf16* __restrict__ Al,
                                              const __bf16* __restrict__ Bh,
                                              const __bf16* __restrict__ Bl,
                                              int M, int N, int K,
                                              const float2* __restrict__ cs,
                                              __bf16* __restrict__ qhi,
                                              __bf16* __restrict__ qlo,
                                              __bf16* __restrict__ khi,
                                              __bf16* __restrict__ klo,
                                              __bf16* __restrict__ v16,
                                              float* __restrict__ C32) {
  __shared__ __align__(16) __bf16 AsH[128 * 32];
  __shared__ __align__(16) __bf16 BsH[128 * 32];
  __shared__ __align__(16) __bf16 AsL[HILO ? 128 * 32 : 4];
  __shared__ __align__(16) __bf16 BsL[HILO ? 128 * 32 : 4];
  const int tid = threadIdx.x, lane = tid & 63, w = tid >> 6;
  const int wm = w >> 1, wn = w & 1;
  const int g = lane >> 4, d = lane & 15;
  const int m0 = blockIdx.y * 128, n0 = blockIdx.x * 128;

  f32x4 acc[4][4];
#pragma unroll
  for (int i = 0; i < 4; ++i)
#pragma unroll
    for (int j = 0; j < 4; ++j) acc[i][j] = (f32x4)(0.0f);

  const int row0 = tid >> 2, kc = tid & 3;
  const int row1 = 64 + row0;

  for (int k0 = 0; k0 < K; k0 += 32) {
    __syncthreads();
    gload_lds16(Ah + (size_t)(m0 + row0) * K + k0 + kc * 8, &AsH[w * 512]);
    gload_lds16(Ah + (size_t)(m0 + row1) * K + k0 + kc * 8, &AsH[2048 + w * 512]);
    gload_lds16(Bh + (size_t)(n0 + row0) * K + k0 + kc * 8, &BsH[w * 512]);
    gload_lds16(Bh + (size_t)(n0 + row1) * K + k0 + kc * 8, &BsH[2048 + w * 512]);
    if constexpr (HILO) {
      gload_lds16(Al + (size_t)(m0 + row0) * K + k0 + kc * 8, &AsL[w * 512]);
      gload_lds16(Al + (size_t)(m0 + row1) * K + k0 + kc * 8, &AsL[2048 + w * 512]);
      gload_lds16(Bl + (size_t)(n0 + row0) * K + k0 + kc * 8, &BsL[w * 512]);
      gload_lds16(Bl + (size_t)(n0 + row1) * K + k0 + kc * 8, &BsL[2048 + w * 512]);
    }
    __syncthreads();
    bf16x8 ah[4], bh[4], al[4], bl[4];
#pragma unroll
    for (int i = 0; i < 4; ++i) {
      ah[i] = *(const bf16x8*)&AsH[(wm * 64 + i * 16 + d) * 32 + g * 8];
      bh[i] = *(const bf16x8*)&BsH[(wn * 64 + i * 16 + d) * 32 + g * 8];
      if constexpr (HILO) {
        al[i] = *(const bf16x8*)&AsL[(wm * 64 + i * 16 + d) * 32 + g * 8];
        bl[i] = *(const bf16x8*)&BsL[(wn * 64 + i * 16 + d) * 32 + g * 8];
      }
    }
#pragma unroll
    for (int i = 0; i < 4; ++i)
#pragma unroll
      for (int j = 0; j < 4; ++j) {
        acc[i][j] = __builtin_amdgcn_mfma_f32_16x16x32_bf16(ah[i], bh[j], acc[i][j], 0, 0, 0);
        if constexpr (HILO) {
          acc[i][j] = __builtin_amdgcn_mfma_f32_16x16x32_bf16(al[i], bh[j], acc[i][j], 0, 0, 0);
          acc[i][j] = __builtin_amdgcn_mfma_f32_16x16x32_bf16(ah[i], bl[j], acc[i][j], 0, 0, 0);
        }
      }
  }

#pragma unroll
  for (int i = 0; i < 4; ++i) {
    const int rbase = m0 + wm * 64 + i * 16 + g * 4;
#pragma unroll
    for (int j = 0; j < 4; ++j) {
      const int col = n0 + wn * 64 + j * 16 + d;
#pragma unroll
      for (int r = 0; r < 4; ++r) {
        const float vv = acc[i][j][r];
        const int row = rbase + r;
        if constexpr (EPI == 0) {
          // RoPE pair partner (cl^1) lives at lane^1, same fragment reg
          const float xp = __shfl_xor(vv, 1);
          const int which = col >> 10;  // 0=q, 1=k
          const int cl = col & 1023;
          const int d2 = cl & 63;
          const int t2 = (row & 127) * 16 + (cl >> 6);  // reshaped position
          float y;
          if (d2 < 32) {
            const float2 cse = cs[t2 * 16 + (d2 >> 1)];
            y = (d2 & 1) ? (vv * cse.x + xp * cse.y) : (vv * cse.x - xp * cse.y);
          } else {
            y = vv;
          }
          if (which == 0) y *= 0.18033688011112042f;  // log2(e)/8: scores in log2 domain
          const __bf16 hi = (__bf16)y;
          const __bf16 lo = (__bf16)(y - (float)hi);
          const size_t off = (size_t)row * 1024 + cl;  // flat == [panel][t2][d2]
          (which ? khi : qhi)[off] = hi;
          (which ? klo : qlo)[off] = lo;
        } else if constexpr (EPI == 1) {
          C32[(size_t)row * N + col] = vv;
        } else {
          v16[(size_t)row * N + col] = (__bf16)vv;
        }
      }
    }
  }
}

// ---------------- GEMM, 64x128 tile (for N=1024 GEMMs: v-proj, out-proj) ----------------
// grid (N/128, M/64) = 512 blocks -> 2 blocks/CU (vs 1 for the 128x128 version):
// the N=1024 GEMMs were running at 1 block/CU = 1 wave/SIMD = zero latency hiding.
template <int EPI>
__global__ __launch_bounds__(256) void k_gemm64(const __bf16* __restrict__ Ah,
                                                const __bf16* __restrict__ Bh,
                                                int M, int N, int K,
                                                __bf16* __restrict__ v16,
                                                float* __restrict__ C32) {
  __shared__ __align__(16) __bf16 As[64 * 32];
  __shared__ __align__(16) __bf16 Bs[128 * 32];
  const int tid = threadIdx.x, lane = tid & 63, w = tid >> 6;
  const int g = lane >> 4, d = lane & 15;
  const int m0 = blockIdx.y * 64, n0 = blockIdx.x * 128;

  f32x4 acc[4][2];
#pragma unroll
  for (int i = 0; i < 4; ++i)
#pragma unroll
    for (int j = 0; j < 2; ++j) acc[i][j] = (f32x4)(0.0f);

  const int row0 = tid >> 2, kc = tid & 3;
  const int row1 = 64 + row0;

  for (int k0 = 0; k0 < K; k0 += 32) {
    __syncthreads();
    gload_lds16(Ah + (size_t)(m0 + row0) * K + k0 + kc * 8, &As[w * 512]);
    gload_lds16(Bh + (size_t)(n0 + row0) * K + k0 + kc * 8, &Bs[w * 512]);
    gload_lds16(Bh + (size_t)(n0 + row1) * K + k0 + kc * 8, &Bs[2048 + w * 512]);
    __syncthreads();
    bf16x8 ah[4], bh[2];
#pragma unroll
    for (int i = 0; i < 4; ++i) ah[i] = *(const bf16x8*)&As[(i * 16 + d) * 32 + g * 8];
#pragma unroll
    for (int j = 0; j < 2; ++j)
      bh[j] = *(const bf16x8*)&Bs[(w * 32 + j * 16 + d) * 32 + g * 8];
#pragma unroll
    for (int i = 0; i < 4; ++i)
#pragma unroll
      for (int j = 0; j < 2; ++j)
        acc[i][j] = __builtin_amdgcn_mfma_f32_16x16x32_bf16(ah[i], bh[j], acc[i][j], 0, 0, 0);
  }

#pragma unroll
  for (int i = 0; i < 4; ++i) {
    const int rbase = m0 + i * 16 + g * 4;
#pragma unroll
    for (int j = 0; j < 2; ++j) {
      const int col = n0 + w * 32 + j * 16 + d;
#pragma unroll
      for (int r = 0; r < 4; ++r) {
        const int row = rbase + r;
        if constexpr (EPI == 1) C32[(size_t)row * N + col] = acc[i][j][r];
        else v16[(size_t)row * N + col] = (__bf16)acc[i][j][r];
      }
    }
  }
}

// ---------------- V transpose: v16[p][t][d] -> v16t[p][d][t] ----------------
__global__ __launch_bounds__(256) void k_vtrans(const __bf16* __restrict__ v16,
                                                __bf16* __restrict__ v16t) {
  __shared__ __bf16 TB[64][72];
  const int p = blockIdx.y, t0 = blockIdx.x * 64;
  const int tid = threadIdx.x;
  const int r = tid >> 2, c4 = (tid & 3) * 16;
  const __bf16* src = v16 + ((size_t)p * 2048 + t0 + r) * 64 + c4;
  bf16x8 A = *(const bf16x8*)src;
  bf16x8 B2 = *(const bf16x8*)(src + 8);
#pragma unroll
  for (int e = 0; e < 8; ++e) {
    TB[c4 + e][r] = A[e];
    TB[c4 + 8 + e][r] = B2[e];
  }
  __syncthreads();
  const int dd = tid >> 2, cc = (tid & 3) * 16;
  __bf16* dst = v16t + ((size_t)p * 64 + dd) * 2048 + t0 + cc;
  *(bf16x8*)dst = *(const bf16x8*)&TB[dd][cc];
  *(bf16x8*)(dst + 8) = *(const bf16x8*)&TB[dd][cc + 8];
}

// ---------------- weight-balanced partition helpers ----------------
// unit (qt, j): weight = 4 (fixed stage/barrier cost) + active-rb count:
// interior (j < 4qt): 20; diagonal p=j-4qt: {20,16,12,8}.
// tileW(qt) = 80qt+56; cumW(qt) = 40qt^2+16qt; panel total 2688 = 16 blocks x 168.
__device__ __forceinline__ void find_unit(int W, int& qt, int& j) {
  qt = 0;
#pragma unroll
  for (int q = 1; q <= 7; ++q)
    if (40 * q * q + 16 * q <= W) qt = q;
  int s = 40 * qt * qt + 16 * qt;
  j = 0;
  while (s < W) {
    int p = j - 4 * qt;
    s += (p < 0) ? 20 : 20 - 4 * p;
    ++j;
  }
}

// ---------------- causal flash attention ----------------
// 512 thr / 8 waves; QBLK=256; KVBLK=64; double-buffered K/V, 1 barrier/tile.
// Weight-balanced packing: block b owns units whose cumulative-weight start is in
// [168b, 168(b+1)) -> at most 2 q-tile segments per block (verified for all 16).
// Slot = b + qt (23 per panel, collision-free); k_combine merges all rows. Masked
// partials self-heal: m=-inf => weight exp2(-inf - M) = 0 in combine.
__global__ __launch_bounds__(512, 4) void k_attn(const __bf16* __restrict__ qhi,
                                                 const __bf16* __restrict__ qlo,
                                                 const __bf16* __restrict__ khi,
                                                 const __bf16* __restrict__ klo,
                                                 const __bf16* __restrict__ v16t,
                                                 __bf16* __restrict__ x16,
                                                 float* __restrict__ po,
                                                 float* __restrict__ pm,
                                                 float* __restrict__ pl_) {
  __shared__ __align__(16) __bf16 KH[2][64 * 64];
  __shared__ __align__(16) __bf16 KL[2][64 * 64];
  __shared__ __align__(16) __bf16 VT[2][64 * 64];
  __shared__ __align__(16) __bf16 PL[8][16 * 72];

  const int b = blockIdx.x, panel = blockIdx.y;
  int qtA, jA, qtE, jE;
  find_unit(168 * b, qtA, jA);
  find_unit(168 * (b + 1), qtE, jE);
  int nseg, jhi0, jhi1 = 0;
  if (qtE == qtA)      { nseg = 1; jhi0 = jE - 1; }
  else if (jE == 0)    { nseg = 1; jhi0 = 4 * qtA + 3; }
  else                 { nseg = 2; jhi0 = 4 * qtA + 3; jhi1 = jE - 1; }

  const int tid = threadIdx.x, lane = tid & 63, w = tid >> 6;
  const int g = lane >> 4, d = lane & 15;
  const size_t hb = (size_t)panel * T_ * 64;

  const int kr = tid >> 3, kc = tid & 7;
  const int swz = (kc ^ (kr & 7)) * 8;
  const __bf16* kB = khi + hb;
  const __bf16* lB = klo + hb;
  const __bf16* vB = v16t + (size_t)panel * (64 * T_);

#define STAGE(j, bb)                                                        \
  {                                                                         \
    gload_lds16(kB + (size_t)((j) * 64 + kr) * 64 + swz, &KH[bb][w * 512]); \
    gload_lds16(lB + (size_t)((j) * 64 + kr) * 64 + swz, &KL[bb][w * 512]); \
    gload_lds16(vB + (size_t)kr * T_ + (j) * 64 + swz, &VT[bb][w * 512]);   \
  }

  int cur = 0;
  STAGE(jA, 0);

#pragma unroll
  for (int seg = 0; seg < 2; ++seg) {
    if (seg >= nseg) break;
    const int qt = qtA + seg;
    const int jlo = seg ? 0 : jA;
    const int jhi = seg ? jhi1 : jhi0;
    const int q0 = qt << 8;

    // per-segment Q fragments (hi + lo persistent in registers)
    bf16x8 qh[2][2], ql[2][2];
#pragma unroll
    for (int rb = 0; rb < 2; ++rb) {
      const int rbi = w * 2 + rb;
      const size_t qrow = hb + (size_t)(q0 + rbi * 16 + d) * 64;
      qh[rb][0] = *(const bf16x8*)&qhi[qrow + g * 8];
      qh[rb][1] = *(const bf16x8*)&qhi[qrow + 32 + g * 8];
      ql[rb][0] = *(const bf16x8*)&qlo[qrow + g * 8];
      ql[rb][1] = *(const bf16x8*)&qlo[qrow + 32 + g * 8];
    }

    f32x4 o[2][4];
#pragma unroll
    for (int rb = 0; rb < 2; ++rb)
#pragma unroll
      for (int i = 0; i < 4; ++i) o[rb][i] = (f32x4)(0.0f);
    float m_[2] = {-__builtin_inff(), -__builtin_inff()};
    float l_[2] = {0.0f, 0.0f};

    for (int j = jlo; j <= jhi; ++j) {
      __syncthreads();  // drains prefetch into buf[cur]; frees buf[cur^1]
      if (j < jhi) {
        STAGE(j + 1, cur ^ 1);
      } else if (!seg && nseg == 2) {
        STAGE(0, cur ^ 1);  // cross-segment prefetch (K/V depend only on j)
      }

#pragma unroll
      for (int rb = 0; rb < 2; ++rb) {
        const int rbi = w * 2 + rb;
        const int qrow0 = q0 + rbi * 16;
        if (j * 64 > qrow0 + 15) continue;  // fully masked rb: skip (partials stay safe)

        f32x4 s[4];
        __builtin_amdgcn_s_setprio(1);
#pragma unroll
        for (int f = 0; f < 4; ++f) {
          f32x4 accs = (f32x4)(0.0f);
          const int colr = f * 16 + d;
#pragma unroll
          for (int ds = 0; ds < 2; ++ds) {
            const int slot = ((ds * 4 + g) ^ (colr & 7)) * 8;
            const bf16x8 kf = *(const bf16x8*)&KH[cur][colr * 64 + slot];
            const bf16x8 lf = *(const bf16x8*)&KL[cur][colr * 64 + slot];
            // SWAPPED: S^T[kv][q] — K is the A-operand, Q the B-operand
            accs = __builtin_amdgcn_mfma_f32_16x16x32_bf16(kf, qh[rb][ds], accs, 0, 0, 0);
            accs = __builtin_amdgcn_mfma_f32_16x16x32_bf16(kf, ql[rb][ds], accs, 0, 0, 0);
            accs = __builtin_amdgcn_mfma_f32_16x16x32_bf16(lf, qh[rb][ds], accs, 0, 0, 0);
          }
          s[f] = accs;
        }
        __builtin_amdgcn_s_setprio(0);

        if (j * 64 + 63 > qrow0) {  // diagonal-crossing tile: mask kv > q
          const int qq = qrow0 + d;
#pragma unroll
          for (int f = 0; f < 4; ++f)
#pragma unroll
            for (int r = 0; r < 4; ++r) {
              const int kv = j * 64 + f * 16 + g * 4 + r;
              if (kv > qq) s[f][r] = -30000.0f;  // sentinel (log2 domain), NaN-safe
            }
        }

        // in-register softmax: lane owns q-row d; reduce in-lane + across g
        float pmax = fmaxf(fmaxf(s[0][0], s[0][1]), fmaxf(s[0][2], s[0][3]));
#pragma unroll
        for (int f = 1; f < 4; ++f)
          pmax = fmaxf(pmax, fmaxf(fmaxf(s[f][0], s[f][1]), fmaxf(s[f][2], s[f][3])));
        pmax = fmaxf(pmax, __shfl_xor(pmax, 16));
        pmax = fmaxf(pmax, __shfl_xor(pmax, 32));

        if (!__all(pmax - m_[rb] <= 11.5f)) {  // defer-max: rescale only on real growth
          const float mnew = fmaxf(m_[rb], pmax);
          const float fac = exp2f(m_[rb] - mnew);
          m_[rb] = mnew;
          float facr[4];
#pragma unroll
          for (int r = 0; r < 4; ++r)
            facr[r] = __shfl(fac, (lane & 48) | (g * 4 + r));  // fac for o-row g*4+r
#pragma unroll
          for (int ni = 0; ni < 4; ++ni)
#pragma unroll
            for (int r = 0; r < 4; ++r) o[rb][ni][r] *= facr[r];
          l_[rb] *= fac;
        }

        float sum = 0.0f;
#pragma unroll
        for (int f = 0; f < 4; ++f) {
          union { __bf16 bb[4]; ushort4 u4; } pk;
#pragma unroll
          for (int r = 0; r < 4; ++r) {
            const float pv = exp2f(s[f][r] - m_[rb]);
            sum += pv;
            pk.bb[r] = (__bf16)pv;
          }
          // P[q=d][kv=f*16+g*4 .. +4] packed: one ds_write_b64
          *(ushort4*)&PL[w][d * 72 + f * 16 + g * 4] = pk.u4;
        }
        sum += __shfl_xor(sum, 16);
        sum += __shfl_xor(sum, 32);
        l_[rb] += sum;

        __builtin_amdgcn_s_setprio(1);
#pragma unroll
        for (int ks = 0; ks < 2; ++ks) {
          const bf16x8 pa = *(const bf16x8*)&PL[w][d * 72 + ks * 32 + g * 8];
#pragma unroll
          for (int ni = 0; ni < 4; ++ni) {
            const bf16x8 vf =
                *(const bf16x8*)&VT[cur][(ni * 16 + d) * 64 + (((ks * 4 + g) ^ (d & 7)) * 8)];
            o[rb][ni] = __builtin_amdgcn_mfma_f32_16x16x32_bf16(pa, vf, o[rb][ni], 0, 0, 0);
          }
        }
        __builtin_amdgcn_s_setprio(0);
      }
      cur ^= 1;
    }

    // partial write for this segment; slot = b + qt (23 per panel)
    const int slot = panel * 23 + b + qt;
#pragma unroll
    for (int rb = 0; rb < 2; ++rb) {
      const int rbi = w * 2 + rb;
#pragma unroll
      for (int ni = 0; ni < 4; ++ni)
#pragma unroll
        for (int r = 0; r < 4; ++r) {
          const int rowin = rbi * 16 + g * 4 + r;
          po[(size_t)slot * 16384 + rowin * 64 + ni * 16 + d] = o[rb][ni][r];
        }
      if (g == 0) {  // lane owns q-row d: one write per row
        pm[slot * 256 + rbi * 16 + d] = m_[rb];
        pl_[slot * 256 + rbi * 16 + d] = l_[rb];
      }
    }
  }
#undef STAGE
}

// ---------------- merge KV-chunk partials for ALL rows (log2 domain) ----------------
// weight-balanced layout: s0 = floor(cumW(qt)/168) + qt,
// nc = floor((cumW(qt+1)-8)/168) - floor(cumW(qt)/168) + 1, cumW = 40qt^2+16qt.
__global__ __launch_bounds__(256) void k_combine(const float* __restrict__ po,
                                                 const float* __restrict__ pm,
                                                 const float* __restrict__ pl_,
                                                 __bf16* __restrict__ x16) {
  const int p = blockIdx.y;
  const int li = blockIdx.x * 256 + threadIdx.x;  // 2048*64 per panel
  const int d = li & 63;
  const int t2 = li >> 6;
  const int qt = t2 >> 8;
  const int rowin = t2 & 255;
  const int cq = 40 * qt * qt + 16 * qt;
  const int nc = (cq + 80 * qt + 48) / 168 - cq / 168 + 1;
  const int s0 = p * 23 + cq / 168 + qt;
  float M = -__builtin_inff();
  for (int s = 0; s < nc; ++s) M = fmaxf(M, pm[(s0 + s) * 256 + rowin]);
  float L = 0.0f, O = 0.0f;
  for (int s = 0; s < nc; ++s) {
    const float ww = exp2f(pm[(s0 + s) * 256 + rowin] - M);
    L += pl_[(s0 + s) * 256 + rowin] * ww;
    O += po[(size_t)(s0 + s) * 16384 + rowin * 64 + d] * ww;
  }
  x16[((size_t)p * T_ + t2) * 64 + d] = (__bf16)(O / L);
}

extern "C" void kernel_launch(void* const* d_in, const int* in_sizes, int n_in,
                              void* d_out, int out_size, void* d_ws, size_t ws_size,
                              hipStream_t stream) {
  const float* query = (const float*)d_in[0];
  const float* win = (const float*)d_in[4];
  const float* wout = (const float*)d_in[5];
  float* out = (float*)d_out;

  const size_t MB = 1024 * 1024;
  const size_t KB = 1024;
  char* ws = (char*)d_ws;
  __bf16* xh = (__bf16*)(ws);                    // 0-8   (dead after v-GEMM)
  __bf16* xl = (__bf16*)(ws + 8 * MB);           // 8-16
  __bf16* whh = (__bf16*)(ws + 16 * MB);         // 16-22
  __bf16* whl = (__bf16*)(ws + 22 * MB);         // 22-28
  __bf16* wob = (__bf16*)(ws + 28 * MB);         // 28-30
  float* pm = (float*)(ws + 30 * MB);            // 736 slots x 256 f32 = 736KB
  float* pl_ = (float*)(ws + 30 * MB + 768 * KB);
  float2* cs = (float2*)(ws + 31 * MB + 512 * KB);  // 256KB, ends at 31.75MB
  float* po = (float*)(ws + 32 * MB);            // 736 slots x 16384 f32 = 46MB -> ends 78MB
  __bf16* qhi = (__bf16*)(ws + 78 * MB);         // 78-86
  __bf16* qlo = (__bf16*)(ws + 86 * MB);         // 86-94
  __bf16* khi = (__bf16*)(ws + 94 * MB);         // 94-102
  __bf16* klo = (__bf16*)(ws + 102 * MB);        // 102-110
  __bf16* x16 = (__bf16*)(ws + 78 * MB);         // alias qhi (dead after k_attn)
  __bf16* v16 = (__bf16*)(ws + 64 * MB);         // live only between v-GEMM and vtrans
  __bf16* v16t = (__bf16*)(ws);                  // over xh, written after v-GEMM

  k_prep<<<8320, 256, 0, stream>>>((const float4*)query, (ushort4*)xh, (ushort4*)xl,
                                   (const float4*)win, (ushort4*)whh, (ushort4*)whl,
                                   (const float4*)wout, (ushort4*)wob, cs);

  // q,k projection with fused RoPE + hi/lo split (q pre-scaled by log2e/8)
  dim3 gqk(16, 32);
  k_gemm<0, true><<<gqk, 256, 0, stream>>>(xh, xl, whh, whl, 4096, 2048, 1024, cs,
                                           qhi, qlo, khi, klo, nullptr, nullptr);
  // v projection (plain bf16), 64-row tiles -> 512 blocks
  dim3 gv(8, 64);
  k_gemm64<2><<<gv, 256, 0, stream>>>(xh, whh + (size_t)2048 * 1024, 4096, 1024, 1024,
                                      v16, nullptr);

  dim3 gt(32, 32);
  k_vtrans<<<gt, 256, 0, stream>>>(v16, v16t);

  dim3 ga(16, 32);  // 512 blocks, weight-balanced (168 weight each)
  k_attn<<<ga, 512, 0, stream>>>(qhi, qlo, khi, klo, v16t, x16, po, pm, pl_);

  dim3 gc(512, 32);  // all 2048 rows combined
  k_combine<<<gc, 256, 0, stream>>>(po, pm, pl_, x16);

  dim3 go(8, 64);  // out projection, 64-row tiles -> 512 blocks
  k_gemm64<1><<<go, 256, 0, stream>>>(x16, wob, 4096, 1024, 1024, nullptr, out);
}

// Round 4
// 204.681 us; speedup vs baseline: 1.8120x; 1.0341x over previous
//
#include <hip/hip_runtime.h>
#include <stdint.h>

#define T_ 2048
#define E_ 1024

typedef __attribute__((ext_vector_type(8))) __bf16 bf16x8;
typedef __attribute__((ext_vector_type(4))) float f32x4;

__device__ __forceinline__ void gload_lds16(const void* g, void* l) {
  __builtin_amdgcn_global_load_lds(
      (const __attribute__((address_space(1))) unsigned int*)g,
      (__attribute__((address_space(3))) unsigned int*)l, 16, 0, 0);
}

// ---------------- fused prep: hi/lo splits + wout cvt + cos/sin table ----------------
__global__ __launch_bounds__(256) void k_prep(const float4* __restrict__ q,
                                              ushort4* __restrict__ xh,
                                              ushort4* __restrict__ xl,
                                              const float4* __restrict__ win,
                                              ushort4* __restrict__ whh,
                                              ushort4* __restrict__ whl,
                                              const float4* __restrict__ wout,
                                              ushort4* __restrict__ wob,
                                              float2* __restrict__ cs) {
  const int b = blockIdx.x, tid = threadIdx.x;
  if (b < 7168) {  // hi/lo split: query (4096 blocks) then in_proj weights (3072)
    const float4* src;
    ushort4 *hi, *lo;
    int i;
    if (b < 4096) { src = q; hi = xh; lo = xl; i = b * 256 + tid; }
    else          { src = win; hi = whh; lo = whl; i = (b - 4096) * 256 + tid; }
    float4 x = src[i];
    float xs[4] = {x.x, x.y, x.z, x.w};
    union { __bf16 bb[4]; ushort4 u; } H, L;
#pragma unroll
    for (int jj = 0; jj < 4; ++jj) {
      __bf16 h = (__bf16)xs[jj];
      H.bb[jj] = h;
      L.bb[jj] = (__bf16)(xs[jj] - (float)h);
    }
    hi[i] = H.u;
    lo[i] = L.u;
  } else if (b < 8192) {  // wout plain cvt (1024 blocks)
    int i = (b - 7168) * 256 + tid;
    float4 x = wout[i];
    float xs[4] = {x.x, x.y, x.z, x.w};
    union { __bf16 bb[4]; ushort4 u; } H;
#pragma unroll
    for (int jj = 0; jj < 4; ++jj) H.bb[jj] = (__bf16)xs[jj];
    wob[i] = H.u;
  } else {  // cos/sin table, double precision (128 blocks)
    int i = (b - 8192) * 256 + tid;
    int t = i >> 4, f = i & 15;
    double inv = pow(10000.0, -(double)f / 16.0);
    double ang = (double)t * inv;
    cs[i] = make_float2((float)cos(ang), (float)sin(ang));
  }
}

// ---------------- GEMM: C(M,N) = A(M,K) * W(N,K)^T, 128x128 tile ----------------
// EPI 0: fused RoPE + q-scale(log2e/8) + bf16 hi/lo split (scores in log2 domain)
template <int EPI, bool HILO>
__global__ __launch_bounds__(256) void k_gemm(const __bf16* __restrict__ Ah,
                                              const __bf16* __restrict__ Al,
                                              const __bf16* __restrict__ Bh,
                                              const __bf16* __restrict__ Bl,
                                              int M, int N, int K,
                                              const float2* __restrict__ cs,
                                              __bf16* __restrict__ qhi,
                                              __bf16* __restrict__ qlo,
                                              __bf16* __restrict__ khi,
                                              __bf16* __restrict__ klo,
                                              __bf16* __restrict__ v16,
                                              float* __restrict__ C32) {
  __shared__ __align__(16) __bf16 AsH[128 * 32];
  __shared__ __align__(16) __bf16 BsH[128 * 32];
  __shared__ __align__(16) __bf16 AsL[HILO ? 128 * 32 : 4];
  __shared__ __align__(16) __bf16 BsL[HILO ? 128 * 32 : 4];
  const int tid = threadIdx.x, lane = tid & 63, w = tid >> 6;
  const int wm = w >> 1, wn = w & 1;
  const int g = lane >> 4, d = lane & 15;
  const int m0 = blockIdx.y * 128, n0 = blockIdx.x * 128;

  f32x4 acc[4][4];
#pragma unroll
  for (int i = 0; i < 4; ++i)
#pragma unroll
    for (int j = 0; j < 4; ++j) acc[i][j] = (f32x4)(0.0f);

  const int row0 = tid >> 2, kc = tid & 3;
  const int row1 = 64 + row0;

  for (int k0 = 0; k0 < K; k0 += 32) {
    __syncthreads();
    gload_lds16(Ah + (size_t)(m0 + row0) * K + k0 + kc * 8, &AsH[w * 512]);
    gload_lds16(Ah + (size_t)(m0 + row1) * K + k0 + kc * 8, &AsH[2048 + w * 512]);
    gload_lds16(Bh + (size_t)(n0 + row0) * K + k0 + kc * 8, &BsH[w * 512]);
    gload_lds16(Bh + (size_t)(n0 + row1) * K + k0 + kc * 8, &BsH[2048 + w * 512]);
    if constexpr (HILO) {
      gload_lds16(Al + (size_t)(m0 + row0) * K + k0 + kc * 8, &AsL[w * 512]);
      gload_lds16(Al + (size_t)(m0 + row1) * K + k0 + kc * 8, &AsL[2048 + w * 512]);
      gload_lds16(Bl + (size_t)(n0 + row0) * K + k0 + kc * 8, &BsL[w * 512]);
      gload_lds16(Bl + (size_t)(n0 + row1) * K + k0 + kc * 8, &BsL[2048 + w * 512]);
    }
    __syncthreads();
    bf16x8 ah[4], bh[4], al[4], bl[4];
#pragma unroll
    for (int i = 0; i < 4; ++i) {
      ah[i] = *(const bf16x8*)&AsH[(wm * 64 + i * 16 + d) * 32 + g * 8];
      bh[i] = *(const bf16x8*)&BsH[(wn * 64 + i * 16 + d) * 32 + g * 8];
      if constexpr (HILO) {
        al[i] = *(const bf16x8*)&AsL[(wm * 64 + i * 16 + d) * 32 + g * 8];
        bl[i] = *(const bf16x8*)&BsL[(wn * 64 + i * 16 + d) * 32 + g * 8];
      }
    }
#pragma unroll
    for (int i = 0; i < 4; ++i)
#pragma unroll
      for (int j = 0; j < 4; ++j) {
        acc[i][j] = __builtin_amdgcn_mfma_f32_16x16x32_bf16(ah[i], bh[j], acc[i][j], 0, 0, 0);
        if constexpr (HILO) {
          acc[i][j] = __builtin_amdgcn_mfma_f32_16x16x32_bf16(al[i], bh[j], acc[i][j], 0, 0, 0);
          acc[i][j] = __builtin_amdgcn_mfma_f32_16x16x32_bf16(ah[i], bl[j], acc[i][j], 0, 0, 0);
        }
      }
  }

#pragma unroll
  for (int i = 0; i < 4; ++i) {
    const int rbase = m0 + wm * 64 + i * 16 + g * 4;
#pragma unroll
    for (int j = 0; j < 4; ++j) {
      const int col = n0 + wn * 64 + j * 16 + d;
#pragma unroll
      for (int r = 0; r < 4; ++r) {
        const float vv = acc[i][j][r];
        const int row = rbase + r;
        if constexpr (EPI == 0) {
          // RoPE pair partner (cl^1) lives at lane^1, same fragment reg
          const float xp = __shfl_xor(vv, 1);
          const int which = col >> 10;  // 0=q, 1=k
          const int cl = col & 1023;
          const int d2 = cl & 63;
          const int t2 = (row & 127) * 16 + (cl >> 6);  // reshaped position
          float y;
          if (d2 < 32) {
            const float2 cse = cs[t2 * 16 + (d2 >> 1)];
            y = (d2 & 1) ? (vv * cse.x + xp * cse.y) : (vv * cse.x - xp * cse.y);
          } else {
            y = vv;
          }
          if (which == 0) y *= 0.18033688011112042f;  // log2(e)/8: scores in log2 domain
          const __bf16 hi = (__bf16)y;
          const __bf16 lo = (__bf16)(y - (float)hi);
          const size_t off = (size_t)row * 1024 + cl;  // flat == [panel][t2][d2]
          (which ? khi : qhi)[off] = hi;
          (which ? klo : qlo)[off] = lo;
        } else if constexpr (EPI == 1) {
          C32[(size_t)row * N + col] = vv;
        } else {
          v16[(size_t)row * N + col] = (__bf16)vv;
        }
      }
    }
  }
}

// ---------------- GEMM, 64x128 tile (for N=1024 GEMMs: v-proj, out-proj) ----------------
// grid (N/128, M/64) = 512 blocks -> 2 blocks/CU (vs 1 for the 128x128 version).
template <int EPI>
__global__ __launch_bounds__(256) void k_gemm64(const __bf16* __restrict__ Ah,
                                                const __bf16* __restrict__ Bh,
                                                int M, int N, int K,
                                                __bf16* __restrict__ v16,
                                                float* __restrict__ C32) {
  __shared__ __align__(16) __bf16 As[64 * 32];
  __shared__ __align__(16) __bf16 Bs[128 * 32];
  const int tid = threadIdx.x, lane = tid & 63, w = tid >> 6;
  const int g = lane >> 4, d = lane & 15;
  const int m0 = blockIdx.y * 64, n0 = blockIdx.x * 128;

  f32x4 acc[4][2];
#pragma unroll
  for (int i = 0; i < 4; ++i)
#pragma unroll
    for (int j = 0; j < 2; ++j) acc[i][j] = (f32x4)(0.0f);

  const int row0 = tid >> 2, kc = tid & 3;
  const int row1 = 64 + row0;

  for (int k0 = 0; k0 < K; k0 += 32) {
    __syncthreads();
    gload_lds16(Ah + (size_t)(m0 + row0) * K + k0 + kc * 8, &As[w * 512]);
    gload_lds16(Bh + (size_t)(n0 + row0) * K + k0 + kc * 8, &Bs[w * 512]);
    gload_lds16(Bh + (size_t)(n0 + row1) * K + k0 + kc * 8, &Bs[2048 + w * 512]);
    __syncthreads();
    bf16x8 ah[4], bh[2];
#pragma unroll
    for (int i = 0; i < 4; ++i) ah[i] = *(const bf16x8*)&As[(i * 16 + d) * 32 + g * 8];
#pragma unroll
    for (int j = 0; j < 2; ++j)
      bh[j] = *(const bf16x8*)&Bs[(w * 32 + j * 16 + d) * 32 + g * 8];
#pragma unroll
    for (int i = 0; i < 4; ++i)
#pragma unroll
      for (int j = 0; j < 2; ++j)
        acc[i][j] = __builtin_amdgcn_mfma_f32_16x16x32_bf16(ah[i], bh[j], acc[i][j], 0, 0, 0);
  }

#pragma unroll
  for (int i = 0; i < 4; ++i) {
    const int rbase = m0 + i * 16 + g * 4;
#pragma unroll
    for (int j = 0; j < 2; ++j) {
      const int col = n0 + w * 32 + j * 16 + d;
#pragma unroll
      for (int r = 0; r < 4; ++r) {
        const int row = rbase + r;
        if constexpr (EPI == 1) C32[(size_t)row * N + col] = acc[i][j][r];
        else v16[(size_t)row * N + col] = (__bf16)acc[i][j][r];
      }
    }
  }
}

// ---------------- V transpose: v16[p][t][d] -> v16t[p][d][t] ----------------
__global__ __launch_bounds__(256) void k_vtrans(const __bf16* __restrict__ v16,
                                                __bf16* __restrict__ v16t) {
  __shared__ __bf16 TB[64][72];
  const int p = blockIdx.y, t0 = blockIdx.x * 64;
  const int tid = threadIdx.x;
  const int r = tid >> 2, c4 = (tid & 3) * 16;
  const __bf16* src = v16 + ((size_t)p * 2048 + t0 + r) * 64 + c4;
  bf16x8 A = *(const bf16x8*)src;
  bf16x8 B2 = *(const bf16x8*)(src + 8);
#pragma unroll
  for (int e = 0; e < 8; ++e) {
    TB[c4 + e][r] = A[e];
    TB[c4 + 8 + e][r] = B2[e];
  }
  __syncthreads();
  const int dd = tid >> 2, cc = (tid & 3) * 16;
  __bf16* dst = v16t + ((size_t)p * 64 + dd) * 2048 + t0 + cc;
  *(bf16x8*)dst = *(const bf16x8*)&TB[dd][cc];
  *(bf16x8*)(dst + 8) = *(const bf16x8*)&TB[dd][cc + 8];
}

// ---------------- causal flash attention ----------------
// 512 thr / 8 waves; QBLK=256; KVBLK=64; double-buffered K/V, 1 barrier/tile.
// ROUND-2 equal-tile packing (measured best: 66.4us): total work per panel =
// 144 kv-tile units; cum(qt)=2qt(qt+1); 16 blocks x exactly 9 units. A block
// spans at most 2 q-tile segments (reload Q, reset m/l/o, write partials).
// Slot = b + qt (23/panel, collision-free). NEW: a segment that covers its
// q-tile's FULL kv range (jlo==0 && jhi==4qt+3, i.e. qt0) writes x16 directly
// and skips partials; k_combine covers only rows 256..2047.
__global__ __launch_bounds__(512, 4) void k_attn(const __bf16* __restrict__ qhi,
                                                 const __bf16* __restrict__ qlo,
                                                 const __bf16* __restrict__ khi,
                                                 const __bf16* __restrict__ klo,
                                                 const __bf16* __restrict__ v16t,
                                                 __bf16* __restrict__ x16,
                                                 float* __restrict__ po,
                                                 float* __restrict__ pm,
                                                 float* __restrict__ pl_) {
  __shared__ __align__(16) __bf16 KH[2][64 * 64];
  __shared__ __align__(16) __bf16 KL[2][64 * 64];
  __shared__ __align__(16) __bf16 VT[2][64 * 64];
  __shared__ __align__(16) __bf16 PL[8][16 * 72];

  const int b = blockIdx.x, panel = blockIdx.y;
  const int u0 = 9 * b;
  // segment A q-tile: largest qt with cum(qt) = 2qt(qt+1) <= u0
  int qtA = 0;
  while (2 * (qtA + 1) * (qtA + 2) <= u0) ++qtA;
  const int cumA = 2 * qtA * (qtA + 1);
  const int cumB = 2 * (qtA + 1) * (qtA + 2);
  const int jloA = u0 - cumA;
  const bool two = (u0 + 9 > cumB);
  const int jhiA = two ? (cumB - 1 - cumA) : (u0 + 8 - cumA);
  const int jhiB = u0 + 8 - cumB;  // valid only if two

  const int tid = threadIdx.x, lane = tid & 63, w = tid >> 6;
  const int g = lane >> 4, d = lane & 15;
  const size_t hb = (size_t)panel * T_ * 64;

  const int kr = tid >> 3, kc = tid & 7;
  const int swz = (kc ^ (kr & 7)) * 8;
  const __bf16* kB = khi + hb;
  const __bf16* lB = klo + hb;
  const __bf16* vB = v16t + (size_t)panel * (64 * T_);

#define STAGE(j, bb)                                                        \
  {                                                                         \
    gload_lds16(kB + (size_t)((j) * 64 + kr) * 64 + swz, &KH[bb][w * 512]); \
    gload_lds16(lB + (size_t)((j) * 64 + kr) * 64 + swz, &KL[bb][w * 512]); \
    gload_lds16(vB + (size_t)kr * T_ + (j) * 64 + swz, &VT[bb][w * 512]);   \
  }

  int cur = 0;
  STAGE(jloA, 0);

  for (int seg = 0; seg < 2; ++seg) {
    if (seg && !two) break;
    const int qt = qtA + seg;
    const int jlo = seg ? 0 : jloA;
    const int jhi = seg ? jhiB : jhiA;
    const int q0 = qt << 8;

    // per-segment Q fragments (hi + lo persistent in registers)
    bf16x8 qh[2][2], ql[2][2];
#pragma unroll
    for (int rb = 0; rb < 2; ++rb) {
      const int rbi = w * 2 + rb;
      const size_t qrow = hb + (size_t)(q0 + rbi * 16 + d) * 64;
      qh[rb][0] = *(const bf16x8*)&qhi[qrow + g * 8];
      qh[rb][1] = *(const bf16x8*)&qhi[qrow + 32 + g * 8];
      ql[rb][0] = *(const bf16x8*)&qlo[qrow + g * 8];
      ql[rb][1] = *(const bf16x8*)&qlo[qrow + 32 + g * 8];
    }

    f32x4 o[2][4];
#pragma unroll
    for (int rb = 0; rb < 2; ++rb)
#pragma unroll
      for (int i = 0; i < 4; ++i) o[rb][i] = (f32x4)(0.0f);
    float m_[2] = {-__builtin_inff(), -__builtin_inff()};
    float l_[2] = {0.0f, 0.0f};

    for (int j = jlo; j <= jhi; ++j) {
      __syncthreads();  // drains prefetch into buf[cur]; frees buf[cur^1]
      if (j < jhi) {
        STAGE(j + 1, cur ^ 1);
      } else if (!seg && two) {
        STAGE(0, cur ^ 1);  // cross-segment prefetch (K/V depend only on j)
      }

#pragma unroll
      for (int rb = 0; rb < 2; ++rb) {
        const int rbi = w * 2 + rb;
        const int qrow0 = q0 + rbi * 16;
        if (j * 64 > qrow0 + 15) continue;  // fully masked rb: skip (partials stay safe)

        f32x4 s[4];
        __builtin_amdgcn_s_setprio(1);
#pragma unroll
        for (int f = 0; f < 4; ++f) {
          f32x4 accs = (f32x4)(0.0f);
          const int colr = f * 16 + d;
#pragma unroll
          for (int ds = 0; ds < 2; ++ds) {
            const int slot = ((ds * 4 + g) ^ (colr & 7)) * 8;
            const bf16x8 kf = *(const bf16x8*)&KH[cur][colr * 64 + slot];
            const bf16x8 lf = *(const bf16x8*)&KL[cur][colr * 64 + slot];
            // SWAPPED: S^T[kv][q] — K is the A-operand, Q the B-operand
            accs = __builtin_amdgcn_mfma_f32_16x16x32_bf16(kf, qh[rb][ds], accs, 0, 0, 0);
            accs = __builtin_amdgcn_mfma_f32_16x16x32_bf16(kf, ql[rb][ds], accs, 0, 0, 0);
            accs = __builtin_amdgcn_mfma_f32_16x16x32_bf16(lf, qh[rb][ds], accs, 0, 0, 0);
          }
          s[f] = accs;
        }
        __builtin_amdgcn_s_setprio(0);

        if (j * 64 + 63 > qrow0) {  // diagonal-crossing tile: mask kv > q
          const int qq = qrow0 + d;
#pragma unroll
          for (int f = 0; f < 4; ++f)
#pragma unroll
            for (int r = 0; r < 4; ++r) {
              const int kv = j * 64 + f * 16 + g * 4 + r;
              if (kv > qq) s[f][r] = -30000.0f;  // sentinel (log2 domain), NaN-safe
            }
        }

        // in-register softmax: lane owns q-row d; reduce in-lane + across g
        float pmax = fmaxf(fmaxf(s[0][0], s[0][1]), fmaxf(s[0][2], s[0][3]));
#pragma unroll
        for (int f = 1; f < 4; ++f)
          pmax = fmaxf(pmax, fmaxf(fmaxf(s[f][0], s[f][1]), fmaxf(s[f][2], s[f][3])));
        pmax = fmaxf(pmax, __shfl_xor(pmax, 16));
        pmax = fmaxf(pmax, __shfl_xor(pmax, 32));

        if (!__all(pmax - m_[rb] <= 11.5f)) {  // defer-max: rescale only on real growth
          const float mnew = fmaxf(m_[rb], pmax);
          const float fac = exp2f(m_[rb] - mnew);
          m_[rb] = mnew;
          float facr[4];
#pragma unroll
          for (int r = 0; r < 4; ++r)
            facr[r] = __shfl(fac, (lane & 48) | (g * 4 + r));  // fac for o-row g*4+r
#pragma unroll
          for (int ni = 0; ni < 4; ++ni)
#pragma unroll
            for (int r = 0; r < 4; ++r) o[rb][ni][r] *= facr[r];
          l_[rb] *= fac;
        }

        float sum = 0.0f;
#pragma unroll
        for (int f = 0; f < 4; ++f) {
          union { __bf16 bb[4]; ushort4 u4; } pk;
#pragma unroll
          for (int r = 0; r < 4; ++r) {
            const float pv = exp2f(s[f][r] - m_[rb]);
            sum += pv;
            pk.bb[r] = (__bf16)pv;
          }
          // P[q=d][kv=f*16+g*4 .. +4] packed: one ds_write_b64
          *(ushort4*)&PL[w][d * 72 + f * 16 + g * 4] = pk.u4;
        }
        sum += __shfl_xor(sum, 16);
        sum += __shfl_xor(sum, 32);
        l_[rb] += sum;

        __builtin_amdgcn_s_setprio(1);
#pragma unroll
        for (int ks = 0; ks < 2; ++ks) {
          const bf16x8 pa = *(const bf16x8*)&PL[w][d * 72 + ks * 32 + g * 8];
#pragma unroll
          for (int ni = 0; ni < 4; ++ni) {
            const bf16x8 vf =
                *(const bf16x8*)&VT[cur][(ni * 16 + d) * 64 + (((ks * 4 + g) ^ (d & 7)) * 8)];
            o[rb][ni] = __builtin_amdgcn_mfma_f32_16x16x32_bf16(pa, vf, o[rb][ni], 0, 0, 0);
          }
        }
        __builtin_amdgcn_s_setprio(0);
      }
      cur ^= 1;
    }

    if (jlo == 0 && jhi == 4 * qt + 3) {
      // segment covers the q-tile's full kv range: final write, no partials.
      // x16 aliases qhi; rows q0..q0+255 are only read by THIS segment (done).
#pragma unroll
      for (int rb = 0; rb < 2; ++rb) {
        const int rbi = w * 2 + rb;
        float lr[4];
#pragma unroll
        for (int r = 0; r < 4; ++r)
          lr[r] = __shfl(l_[rb], (lane & 48) | (g * 4 + r));
#pragma unroll
        for (int ni = 0; ni < 4; ++ni)
#pragma unroll
          for (int r = 0; r < 4; ++r) {
            const size_t row = hb + (size_t)(q0 + rbi * 16 + g * 4 + r) * 64;
            x16[row + ni * 16 + d] = (__bf16)(o[rb][ni][r] / lr[r]);
          }
      }
    } else {
      // partial write for this segment; slot = b + qt (23 per panel)
      const int slot = panel * 23 + b + qt;
#pragma unroll
      for (int rb = 0; rb < 2; ++rb) {
        const int rbi = w * 2 + rb;
#pragma unroll
        for (int ni = 0; ni < 4; ++ni)
#pragma unroll
          for (int r = 0; r < 4; ++r) {
            const int rowin = rbi * 16 + g * 4 + r;
            po[(size_t)slot * 16384 + rowin * 64 + ni * 16 + d] = o[rb][ni][r];
          }
        if (g == 0) {  // lane owns q-row d: one write per row
          pm[slot * 256 + rbi * 16 + d] = m_[rb];
          pl_[slot * 256 + rbi * 16 + d] = l_[rb];
        }
      }
    }
  }
#undef STAGE
}

// ---------------- merge KV-chunk partials for rows 256..2047 (log2 domain) ----------------
// qt's chunks occupy slots [s0, s0+nc) with s0 = cum(qt)/9 + qt,
// nc = (cum(qt)+4qt+3)/9 - cum(qt)/9 + 1   (cum(qt) = 2qt(qt+1)).  qt=0 is
// direct-written by k_attn and skipped here.
__global__ __launch_bounds__(256) void k_combine(const float* __restrict__ po,
                                                 const float* __restrict__ pm,
                                                 const float* __restrict__ pl_,
                                                 __bf16* __restrict__ x16) {
  const int p = blockIdx.y;
  const int li = blockIdx.x * 256 + threadIdx.x;  // 1792*64 per panel
  const int d = li & 63;
  const int t2 = 256 + (li >> 6);
  const int qt = t2 >> 8;                          // 1..7
  const int rowin = t2 & 255;
  const int cq = 2 * qt * (qt + 1);
  const int nc = (cq + 4 * qt + 3) / 9 - cq / 9 + 1;
  const int s0 = p * 23 + cq / 9 + qt;
  float M = -__builtin_inff();
  for (int s = 0; s < nc; ++s) M = fmaxf(M, pm[(s0 + s) * 256 + rowin]);
  float L = 0.0f, O = 0.0f;
  for (int s = 0; s < nc; ++s) {
    const float ww = exp2f(pm[(s0 + s) * 256 + rowin] - M);
    L += pl_[(s0 + s) * 256 + rowin] * ww;
    O += po[(size_t)(s0 + s) * 16384 + rowin * 64 + d] * ww;
  }
  x16[((size_t)p * T_ + t2) * 64 + d] = (__bf16)(O / L);
}

extern "C" void kernel_launch(void* const* d_in, const int* in_sizes, int n_in,
                              void* d_out, int out_size, void* d_ws, size_t ws_size,
                              hipStream_t stream) {
  const float* query = (const float*)d_in[0];
  const float* win = (const float*)d_in[4];
  const float* wout = (const float*)d_in[5];
  float* out = (float*)d_out;

  const size_t MB = 1024 * 1024;
  const size_t KB = 1024;
  char* ws = (char*)d_ws;
  __bf16* xh = (__bf16*)(ws);                    // 0-8   (dead after v-GEMM)
  __bf16* xl = (__bf16*)(ws + 8 * MB);           // 8-16
  __bf16* whh = (__bf16*)(ws + 16 * MB);         // 16-22
  __bf16* whl = (__bf16*)(ws + 22 * MB);         // 22-28
  __bf16* wob = (__bf16*)(ws + 28 * MB);         // 28-30
  float* pm = (float*)(ws + 30 * MB);            // 736 slots x 256 f32 = 736KB
  float* pl_ = (float*)(ws + 30 * MB + 768 * KB);
  float2* cs = (float2*)(ws + 31 * MB + 512 * KB);  // 256KB, ends at 31.75MB
  float* po = (float*)(ws + 32 * MB);            // 736 slots x 16384 f32 = 46MB -> ends 78MB
  __bf16* qhi = (__bf16*)(ws + 78 * MB);         // 78-86
  __bf16* qlo = (__bf16*)(ws + 86 * MB);         // 86-94
  __bf16* khi = (__bf16*)(ws + 94 * MB);         // 94-102
  __bf16* klo = (__bf16*)(ws + 102 * MB);        // 102-110
  __bf16* x16 = (__bf16*)(ws + 78 * MB);         // alias qhi (dead after k_attn)
  __bf16* v16 = (__bf16*)(ws + 64 * MB);         // live only between v-GEMM and vtrans
  __bf16* v16t = (__bf16*)(ws);                  // over xh, written after v-GEMM

  k_prep<<<8320, 256, 0, stream>>>((const float4*)query, (ushort4*)xh, (ushort4*)xl,
                                   (const float4*)win, (ushort4*)whh, (ushort4*)whl,
                                   (const float4*)wout, (ushort4*)wob, cs);

  // q,k projection with fused RoPE + hi/lo split (q pre-scaled by log2e/8)
  dim3 gqk(16, 32);
  k_gemm<0, true><<<gqk, 256, 0, stream>>>(xh, xl, whh, whl, 4096, 2048, 1024, cs,
                                           qhi, qlo, khi, klo, nullptr, nullptr);
  // v projection (plain bf16), 64-row tiles -> 512 blocks
  dim3 gv(8, 64);
  k_gemm64<2><<<gv, 256, 0, stream>>>(xh, whh + (size_t)2048 * 1024, 4096, 1024, 1024,
                                      v16, nullptr);

  dim3 gt(32, 32);
  k_vtrans<<<gt, 256, 0, stream>>>(v16, v16t);

  dim3 ga(16, 32);  // 512 blocks == exact 2-blocks/CU residency, 9 units each
  k_attn<<<ga, 512, 0, stream>>>(qhi, qlo, khi, klo, v16t, x16, po, pm, pl_);

  dim3 gc(448, 32);  // rows 256..2047 (qt0 direct-written in k_attn)
  k_combine<<<gc, 256, 0, stream>>>(po, pm, pl_, x16);

  dim3 go(8, 64);  // out projection, 64-row tiles -> 512 blocks
  k_gemm64<1><<<go, 256, 0, stream>>>(x16, wob, 4096, 1024, 1024, nullptr, out);
}